// Round 8
// baseline (355.457 us; speedup 1.0000x reference)
//
#include <hip/hip_runtime.h>
#include <stdint.h>

typedef __bf16 bf16x8 __attribute__((ext_vector_type(8)));
typedef short s16x8 __attribute__((ext_vector_type(8)));
typedef short s16x4 __attribute__((ext_vector_type(4)));
typedef float f32x4 __attribute__((ext_vector_type(4)));
typedef unsigned short u16;

#define K_DIM 1024

static __device__ __forceinline__ u16 f2bf(float f) {
    uint32_t x = __float_as_uint(f);
    x += 0x7fffu + ((x >> 16) & 1u);
    return (u16)(x >> 16);
}

static __device__ __forceinline__ f32x4 mfma16(s16x8 a, s16x8 b, f32x4 c) {
    return __builtin_amdgcn_mfma_f32_16x16x32_bf16(
        __builtin_bit_cast(bf16x8, a), __builtin_bit_cast(bf16x8, b), c, 0, 0, 0);
}

static __device__ __forceinline__ void gload16(const u16* g, u16* l) {
    __builtin_amdgcn_global_load_lds(
        (const __attribute__((address_space(1))) void*)g,
        (__attribute__((address_space(3))) void*)l,
        16, 0, 0);
}

static __device__ __forceinline__ uint32_t cvt_pk_bf16(float lo, float hi) {
    uint32_t r;
    asm("v_cvt_pk_bf16_f32 %0, %1, %2" : "=v"(r) : "v"(lo), "v"(hi));
    return r;
}

static __device__ __forceinline__ float fexp2(float x) {
#if __has_builtin(__builtin_amdgcn_exp2f)
    return __builtin_amdgcn_exp2f(x);
#else
    return __expf(x * 0.69314718056f);
#endif
}

// ---------------- fp32 -> bf16 conversion ----------------
__global__ void cvt_f2bf(const float* __restrict__ in, u16* __restrict__ out, int n4) {
    int stride = gridDim.x * blockDim.x;
    for (int i = blockIdx.x * blockDim.x + threadIdx.x; i < n4; i += stride) {
        float4 f = ((const float4*)in)[i];
        ushort4 o;
        o.x = f2bf(f.x); o.y = f2bf(f.y); o.z = f2bf(f.z); o.w = f2bf(f.w);
        ((ushort4*)out)[i] = o;
    }
}

// ---------------- QKV projection GEMM (r3 known-good structure) ----------------
__global__ __launch_bounds__(256) void gemm_qkv(
    const u16* __restrict__ A, const u16* __restrict__ B,
    const float* __restrict__ bias,
    u16* __restrict__ qo, u16* __restrict__ ko, u16* __restrict__ vto)
{
    __shared__ u16 As[128 * 32];
    __shared__ u16 Bs[128 * 32];
    const int tid = threadIdx.x;
    const int w = tid >> 6, l = tid & 63;
    const int lr = l & 15, lc = l >> 4;
    const int m0 = blockIdx.x * 128, n0 = blockIdx.y * 128;
    const int wm = (w >> 1) * 64, wn = (w & 1) * 64;

    const int srow = w * 32 + (l >> 2);
    const int scol = (l & 3) * 8;
    const u16* gA = A + (size_t)(m0 + srow) * K_DIM + scol;
    const u16* gB = B + (size_t)(n0 + srow) * K_DIM + scol;
    u16* lA = &As[w * 1024];
    u16* lB = &Bs[w * 1024];

    f32x4 acc[4][4] = {};

    for (int k0 = 0; k0 < K_DIM; k0 += 32) {
        __syncthreads();
        gload16(gA + k0, lA);
        gload16(gA + 16 * K_DIM + k0, lA + 512);
        gload16(gB + k0, lB);
        gload16(gB + 16 * K_DIM + k0, lB + 512);
        __syncthreads();
        s16x8 a[4], b[4];
        #pragma unroll
        for (int i = 0; i < 4; ++i)
            a[i] = *(const s16x8*)&As[(wm + i * 16 + lr) * 32 + lc * 8];
        #pragma unroll
        for (int j = 0; j < 4; ++j)
            b[j] = *(const s16x8*)&Bs[(wn + j * 16 + lr) * 32 + lc * 8];
        #pragma unroll
        for (int i = 0; i < 4; ++i)
            #pragma unroll
            for (int j = 0; j < 4; ++j)
                acc[i][j] = mfma16(a[i], b[j], acc[i][j]);
    }

    #pragma unroll
    for (int j = 0; j < 4; ++j) {
        const int n = n0 + wn + j * 16 + lr;
        const float bv = bias[n];
        const int sec = n >> 10;
        const int h = (n & 1023) >> 6, d = n & 63;
        #pragma unroll
        for (int i = 0; i < 4; ++i) {
            #pragma unroll
            for (int r = 0; r < 4; ++r) {
                const int m = m0 + wm + i * 16 + lc * 4 + r;
                const int bb = m >> 11, s = m & 2047;
                float v = acc[i][j][r] + bv;
                if (sec == 0)
                    qo[((size_t)((bb * 16 + h) * 2048 + s)) * 64 + d] = f2bf(v * 0.18033688f);
                else if (sec == 1)
                    ko[((size_t)((bb * 16 + h) * 2048 + s)) * 64 + d] = f2bf(v);
                else
                    vto[((size_t)((bb * 16 + h) * 64 + d)) * 2048 + s] = f2bf(v);
            }
        }
    }
}

// ---------------- flash attention (causal, static-max, swapped QK^T) ----------------
// QBLK=16: one wave = 16 q-rows, chunk pair (c, 127-c) -> exactly 33 kv-blocks
// per wave. 4096 waves (grid 64x16 x 4 waves) = 4 waves/SIMD for latency hiding.
// Same verified structure as r6, with the q-tile dimension removed.
// S^T = mfma(K, Q): lane (lr,lc) holds S[kv=4*lc+r][q=lr] per 16-kv tile.
__global__ __launch_bounds__(256, 4) void attn_fwd(
    const u16* __restrict__ q, const u16* __restrict__ k,
    const u16* __restrict__ vt, u16* __restrict__ ao)
{
    __shared__ u16 plds[4 * 16 * 72];
    const int w = threadIdx.x >> 6, l = threadIdx.x & 63;
    const int lr = l & 15, lc = l >> 4;
    const int bh = blockIdx.x;               // fast dim -> spreads heads across CUs
    const int c = blockIdx.y * 4 + w;        // chunk 0..63 (pair partner 127-c)
    const u16* qp = q + (size_t)bh * 2048 * 64;
    const u16* kp = k + (size_t)bh * 2048 * 64;
    const u16* vp = vt + (size_t)bh * 64 * 2048;
    u16* pl = &plds[w * 16 * 72];
    const int bb = bh >> 4, h = bh & 15;

    for (int pass = 0; pass < 2; ++pass) {
        const int q0 = (pass ? (127 - c) : c) * 16;

        s16x8 aQ[2];
        #pragma unroll
        for (int kk = 0; kk < 2; ++kk)
            aQ[kk] = *(const s16x8*)&qp[(q0 + lr) * 64 + kk * 32 + lc * 8];

        f32x4 O[4] = {};
        f32x4 lsv = {};
        const int nb = (q0 >> 6) + 1;

        for (int t = 0; t < nb; ++t) {
            const int c0 = t * 64;
            // S^T = K . Q^T  (rows = kv, cols = q)
            f32x4 s[4] = {};
            #pragma unroll
            for (int j = 0; j < 4; ++j) {
                s16x8 k0 = *(const s16x8*)&kp[(c0 + j * 16 + lr) * 64 + lc * 8];
                s16x8 k1 = *(const s16x8*)&kp[(c0 + j * 16 + lr) * 64 + 32 + lc * 8];
                s[j] = mfma16(k0, aQ[0], s[j]);
                s[j] = mfma16(k1, aQ[1], s[j]);
            }
            // causal mask (diagonal block only): kv > q -> -inf
            if (t == nb - 1) {
                const int qrow = q0 + lr;
                #pragma unroll
                for (int j = 0; j < 4; ++j) {
                    const int kvb = c0 + j * 16 + lc * 4;
                    #pragma unroll
                    for (int r = 0; r < 4; ++r)
                        if (kvb + r > qrow) s[j][r] = -1e30f;
                }
            }
            // p = exp2(s); in-lane partial row sums; pack bf16; LDS b64 writes (stride 72)
            #pragma unroll
            for (int j = 0; j < 4; ++j)
                #pragma unroll
                for (int r = 0; r < 4; ++r)
                    s[j][r] = fexp2(s[j][r]);
            lsv += (s[0] + s[1]) + (s[2] + s[3]);
            #pragma unroll
            for (int j = 0; j < 4; ++j) {
                uint2 pk;
                pk.x = cvt_pk_bf16(s[j][0], s[j][1]);
                pk.y = cvt_pk_bf16(s[j][2], s[j][3]);
                *(s16x4*)&pl[lr * 72 + j * 16 + lc * 4] = __builtin_bit_cast(s16x4, pk);
            }
            // PV: A = P rows q (from LDS), B = V^T rows d
            s16x8 aP[2];
            #pragma unroll
            for (int kk = 0; kk < 2; ++kk)
                aP[kk] = *(const s16x8*)&pl[lr * 72 + kk * 32 + lc * 8];
            #pragma unroll
            for (int jd = 0; jd < 4; ++jd) {
                s16x8 v0 = *(const s16x8*)&vp[(jd * 16 + lr) * 2048 + c0 + lc * 8];
                s16x8 v1 = *(const s16x8*)&vp[(jd * 16 + lr) * 2048 + c0 + 32 + lc * 8];
                O[jd] = mfma16(aP[0], v0, O[jd]);
                O[jd] = mfma16(aP[1], v1, O[jd]);
            }
        }

        // finalize: reduce ls across lc groups (q row = lr), invert, redistribute
        float t2 = (lsv[0] + lsv[1]) + (lsv[2] + lsv[3]);
        t2 += __shfl_xor(t2, 16);
        t2 += __shfl_xor(t2, 32);
        const float lsr = 1.0f / t2;
        float inv[4];
        #pragma unroll
        for (int r = 0; r < 4; ++r)
            inv[r] = __shfl(lsr, lc * 4 + r);

        #pragma unroll
        for (int jd = 0; jd < 4; ++jd)
            #pragma unroll
            for (int r = 0; r < 4; ++r) {
                const int srow = q0 + lc * 4 + r;
                ao[((size_t)(bb * 2048 + srow)) * 1024 + h * 64 + jd * 16 + lr] =
                    f2bf(O[jd][r] * inv[r]);
            }
    }
}

// ---------------- output projection GEMM (r3 known-good structure) ----------------
__global__ __launch_bounds__(256) void gemm_out(
    const u16* __restrict__ A, const u16* __restrict__ B,
    const float* __restrict__ bias, float* __restrict__ out)
{
    __shared__ u16 As[128 * 32];
    __shared__ u16 Bs[128 * 32];
    const int tid = threadIdx.x;
    const int w = tid >> 6, l = tid & 63;
    const int lr = l & 15, lc = l >> 4;
    const int m0 = blockIdx.x * 128, n0 = blockIdx.y * 128;
    const int wm = (w >> 1) * 64, wn = (w & 1) * 64;

    const int srow = w * 32 + (l >> 2);
    const int scol = (l & 3) * 8;
    const u16* gA = A + (size_t)(m0 + srow) * K_DIM + scol;
    const u16* gB = B + (size_t)(n0 + srow) * K_DIM + scol;
    u16* lA = &As[w * 1024];
    u16* lB = &Bs[w * 1024];

    f32x4 acc[4][4] = {};

    for (int k0 = 0; k0 < K_DIM; k0 += 32) {
        __syncthreads();
        gload16(gA + k0, lA);
        gload16(gA + 16 * K_DIM + k0, lA + 512);
        gload16(gB + k0, lB);
        gload16(gB + 16 * K_DIM + k0, lB + 512);
        __syncthreads();
        s16x8 a[4], b[4];
        #pragma unroll
        for (int i = 0; i < 4; ++i)
            a[i] = *(const s16x8*)&As[(wm + i * 16 + lr) * 32 + lc * 8];
        #pragma unroll
        for (int j = 0; j < 4; ++j)
            b[j] = *(const s16x8*)&Bs[(wn + j * 16 + lr) * 32 + lc * 8];
        #pragma unroll
        for (int i = 0; i < 4; ++i)
            #pragma unroll
            for (int j = 0; j < 4; ++j)
                acc[i][j] = mfma16(a[i], b[j], acc[i][j]);
    }

    #pragma unroll
    for (int j = 0; j < 4; ++j) {
        const int n = n0 + wn + j * 16 + lr;
        const float bv = bias[n];
        #pragma unroll
        for (int i = 0; i < 4; ++i) {
            #pragma unroll
            for (int r = 0; r < 4; ++r) {
                const int m = m0 + wm + i * 16 + lc * 4 + r;
                out[(size_t)m * 1024 + n] = acc[i][j][r] + bv;
            }
        }
    }
}

// ---------------- launcher ----------------
extern "C" void kernel_launch(void* const* d_in, const int* in_sizes, int n_in,
                              void* d_out, int out_size, void* d_ws, size_t ws_size,
                              hipStream_t stream) {
    const float* x     = (const float*)d_in[0];
    const float* w_qkv = (const float*)d_in[1];
    const float* b_qkv = (const float*)d_in[2];
    const float* w_out = (const float*)d_in[3];
    const float* b_out = (const float*)d_in[4];
    float* out = (float*)d_out;

    char* ws = (char*)d_ws;
    u16* xb   = (u16*)(ws);                    // 8192x1024 bf16  (16 MB)
    u16* wqb  = (u16*)(ws + 16777216);         // 3072x1024 bf16  (6 MB)
    u16* wob  = (u16*)(ws + 23068672);         // 1024x1024 bf16  (2 MB)
    u16* qws  = (u16*)(ws + 25165824);         // [64][2048][64]  (16 MB)
    u16* kws  = (u16*)(ws + 41943040);         // [64][2048][64]  (16 MB)
    u16* vtws = (u16*)(ws + 58720256);         // [64][64][2048]  (16 MB)
    u16* attn = (u16*)(ws + 75497472);         // 8192x1024 bf16  (16 MB)

    cvt_f2bf<<<dim3(2048), 256, 0, stream>>>(x,     xb,  8388608 / 4);
    cvt_f2bf<<<dim3(2048), 256, 0, stream>>>(w_qkv, wqb, 3145728 / 4);
    cvt_f2bf<<<dim3(1024), 256, 0, stream>>>(w_out, wob, 1048576 / 4);

    gemm_qkv<<<dim3(64, 24), 256, 0, stream>>>(xb, wqb, b_qkv, qws, kws, vtws);
    attn_fwd<<<dim3(64, 16), 256, 0, stream>>>(qws, kws, vtws, attn);
    gemm_out<<<dim3(64, 8), 256, 0, stream>>>(attn, wob, b_out, out);
}

// Round 9
// 183.317 us; speedup vs baseline: 1.9390x; 1.9390x over previous
//
#include <hip/hip_runtime.h>
#include <stdint.h>

typedef __bf16 bf16x8 __attribute__((ext_vector_type(8)));
typedef short s16x8 __attribute__((ext_vector_type(8)));
typedef short s16x4 __attribute__((ext_vector_type(4)));
typedef float f32x4 __attribute__((ext_vector_type(4)));
typedef unsigned short u16;

#define K_DIM 1024

static __device__ __forceinline__ u16 f2bf(float f) {
    uint32_t x = __float_as_uint(f);
    x += 0x7fffu + ((x >> 16) & 1u);
    return (u16)(x >> 16);
}

static __device__ __forceinline__ f32x4 mfma16(s16x8 a, s16x8 b, f32x4 c) {
    return __builtin_amdgcn_mfma_f32_16x16x32_bf16(
        __builtin_bit_cast(bf16x8, a), __builtin_bit_cast(bf16x8, b), c, 0, 0, 0);
}

static __device__ __forceinline__ void gload16(const u16* g, u16* l) {
    __builtin_amdgcn_global_load_lds(
        (const __attribute__((address_space(1))) void*)g,
        (__attribute__((address_space(3))) void*)l,
        16, 0, 0);
}

static __device__ __forceinline__ uint32_t cvt_pk_bf16(float lo, float hi) {
    uint32_t r;
    asm("v_cvt_pk_bf16_f32 %0, %1, %2" : "=v"(r) : "v"(lo), "v"(hi));
    return r;
}

static __device__ __forceinline__ float fexp2(float x) {
#if __has_builtin(__builtin_amdgcn_exp2f)
    return __builtin_amdgcn_exp2f(x);
#else
    return __expf(x * 0.69314718056f);
#endif
}

// ---------------- fp32 -> bf16 conversion ----------------
__global__ void cvt_f2bf(const float* __restrict__ in, u16* __restrict__ out, int n4) {
    int stride = gridDim.x * blockDim.x;
    for (int i = blockIdx.x * blockDim.x + threadIdx.x; i < n4; i += stride) {
        float4 f = ((const float4*)in)[i];
        ushort4 o;
        o.x = f2bf(f.x); o.y = f2bf(f.y); o.z = f2bf(f.z); o.w = f2bf(f.w);
        ((ushort4*)out)[i] = o;
    }
}

// ---------------- QKV projection GEMM (r3 known-good structure) ----------------
__global__ __launch_bounds__(256) void gemm_qkv(
    const u16* __restrict__ A, const u16* __restrict__ B,
    const float* __restrict__ bias,
    u16* __restrict__ qo, u16* __restrict__ ko, u16* __restrict__ vto)
{
    __shared__ u16 As[128 * 32];
    __shared__ u16 Bs[128 * 32];
    const int tid = threadIdx.x;
    const int w = tid >> 6, l = tid & 63;
    const int lr = l & 15, lc = l >> 4;
    const int m0 = blockIdx.x * 128, n0 = blockIdx.y * 128;
    const int wm = (w >> 1) * 64, wn = (w & 1) * 64;

    const int srow = w * 32 + (l >> 2);
    const int scol = (l & 3) * 8;
    const u16* gA = A + (size_t)(m0 + srow) * K_DIM + scol;
    const u16* gB = B + (size_t)(n0 + srow) * K_DIM + scol;
    u16* lA = &As[w * 1024];
    u16* lB = &Bs[w * 1024];

    f32x4 acc[4][4] = {};

    for (int k0 = 0; k0 < K_DIM; k0 += 32) {
        __syncthreads();
        gload16(gA + k0, lA);
        gload16(gA + 16 * K_DIM + k0, lA + 512);
        gload16(gB + k0, lB);
        gload16(gB + 16 * K_DIM + k0, lB + 512);
        __syncthreads();
        s16x8 a[4], b[4];
        #pragma unroll
        for (int i = 0; i < 4; ++i)
            a[i] = *(const s16x8*)&As[(wm + i * 16 + lr) * 32 + lc * 8];
        #pragma unroll
        for (int j = 0; j < 4; ++j)
            b[j] = *(const s16x8*)&Bs[(wn + j * 16 + lr) * 32 + lc * 8];
        #pragma unroll
        for (int i = 0; i < 4; ++i)
            #pragma unroll
            for (int j = 0; j < 4; ++j)
                acc[i][j] = mfma16(a[i], b[j], acc[i][j]);
    }

    #pragma unroll
    for (int j = 0; j < 4; ++j) {
        const int n = n0 + wn + j * 16 + lr;
        const float bv = bias[n];
        const int sec = n >> 10;
        const int h = (n & 1023) >> 6, d = n & 63;
        #pragma unroll
        for (int i = 0; i < 4; ++i) {
            #pragma unroll
            for (int r = 0; r < 4; ++r) {
                const int m = m0 + wm + i * 16 + lc * 4 + r;
                const int bb = m >> 11, s = m & 2047;
                float v = acc[i][j][r] + bv;
                if (sec == 0)
                    qo[((size_t)((bb * 16 + h) * 2048 + s)) * 64 + d] = f2bf(v * 0.18033688f);
                else if (sec == 1)
                    ko[((size_t)((bb * 16 + h) * 2048 + s)) * 64 + d] = f2bf(v);
                else
                    vto[((size_t)((bb * 16 + h) * 64 + d)) * 2048 + s] = f2bf(v);
            }
        }
    }
}

// ---------------- flash attention (causal, static-max, swapped QK^T) ----------------
// Block = 128 contiguous q-rows of one head (4 waves x QBLK=32), chunk pair
// (C, 15-C) -> exactly 34 kv-iterations/block. Per iteration the block stages
// the shared K-tile and V^T-tile into LDS in FRAGMENT-MAJOR layout via
// global_load_lds (per-lane global source = that lane's MFMA fragment element,
// wave-uniform LDS dest; lane i lands at dest + i*16B) -> all ds_read_b128
// are lane-consecutive 16B (conflict-free), and global K/V traffic is shared
// 4 ways. Causal skip/mask is per-wave uniform; barriers are never skipped.
__global__ __launch_bounds__(256, 2) void attn_fwd(
    const u16* __restrict__ q, const u16* __restrict__ k,
    const u16* __restrict__ vt, u16* __restrict__ ao)
{
    __shared__ u16 kt[8 * 512];        // K tile, fragment-major: frag g=(j*2+kk) at g*512
    __shared__ u16 vtl[8 * 512];       // V^T tile, frag g=(jd*2+kk) at g*512
    __shared__ u16 plds[4 * 32 * 72];  // per-wave P buffers
    const int w = threadIdx.x >> 6, l = threadIdx.x & 63;
    const int lr = l & 15, lc = l >> 4;
    const int bh = blockIdx.x;
    const int cp = blockIdx.y;                 // pair id 0..7
    const u16* qp = q + (size_t)bh * 2048 * 64;
    const u16* kp = k + (size_t)bh * 2048 * 64;
    const u16* vp = vt + (size_t)bh * 64 * 2048;
    u16* pl = &plds[w * 2304];
    const int bb = bh >> 4, h = bh & 15;

    for (int pass = 0; pass < 2; ++pass) {
        const int C = pass ? (15 - cp) : cp;   // 128-row chunk id 0..15
        const int Q0 = C * 128;
        const int q0 = Q0 + w * 32;            // this wave's first q-row
        const int nb = 2 * C + 2;              // kv blocks of 64 for the whole block
        const int diag = 2 * C + (w >> 1);     // this wave's diagonal iteration

        s16x8 aQ[2][2];
        #pragma unroll
        for (int i = 0; i < 2; ++i)
            #pragma unroll
            for (int kk = 0; kk < 2; ++kk)
                aQ[i][kk] = *(const s16x8*)&qp[(q0 + i * 16 + lr) * 64 + kk * 32 + lc * 8];

        f32x4 O[2][4] = {};
        f32x4 lsv[2] = {};

        for (int t = 0; t < nb; ++t) {
            const int c0 = t * 64;
            __syncthreads();                   // previous iteration's tile reads done
            // cooperative staging: wave 0/1 -> K frags, wave 2/3 -> V frags
            if (w < 2) {
                #pragma unroll
                for (int gi = 0; gi < 4; ++gi) {
                    const int g = w * 4 + gi;          // 0..7
                    const int j = g >> 1, kk = g & 1;
                    gload16(kp + (c0 + j * 16 + lr) * 64 + kk * 32 + lc * 8,
                            &kt[g * 512]);
                }
            } else {
                #pragma unroll
                for (int gi = 0; gi < 4; ++gi) {
                    const int g = (w - 2) * 4 + gi;    // 0..7
                    const int jd = g >> 1, kk = g & 1;
                    gload16(vp + (jd * 16 + lr) * 2048 + c0 + kk * 32 + lc * 8,
                            &vtl[g * 512]);
                }
            }
            __syncthreads();                   // tiles ready (vmcnt drained at barrier)

            if (t <= diag) {
                // S^T = K . Q^T  (rows = kv, cols = q)
                f32x4 s[2][4] = {};
                #pragma unroll
                for (int j = 0; j < 4; ++j) {
                    s16x8 k0 = *(const s16x8*)&kt[(j * 2 + 0) * 512 + l * 8];
                    s16x8 k1 = *(const s16x8*)&kt[(j * 2 + 1) * 512 + l * 8];
                    s[0][j] = mfma16(k0, aQ[0][0], s[0][j]);
                    s[0][j] = mfma16(k1, aQ[0][1], s[0][j]);
                    s[1][j] = mfma16(k0, aQ[1][0], s[1][j]);
                    s[1][j] = mfma16(k1, aQ[1][1], s[1][j]);
                }
                // causal mask on this wave's diagonal iteration only
                if (t == diag) {
                    #pragma unroll
                    for (int i = 0; i < 2; ++i) {
                        const int qrow = q0 + i * 16 + lr;
                        #pragma unroll
                        for (int j = 0; j < 4; ++j) {
                            const int kvb = c0 + j * 16 + lc * 4;
                            #pragma unroll
                            for (int r = 0; r < 4; ++r)
                                if (kvb + r > qrow) s[i][j][r] = -1e30f;
                        }
                    }
                }
                // p = exp2(s); in-lane partial row sums; pack bf16; LDS b64 writes
                #pragma unroll
                for (int i = 0; i < 2; ++i) {
                    #pragma unroll
                    for (int j = 0; j < 4; ++j)
                        #pragma unroll
                        for (int r = 0; r < 4; ++r)
                            s[i][j][r] = fexp2(s[i][j][r]);
                    lsv[i] += (s[i][0] + s[i][1]) + (s[i][2] + s[i][3]);
                    #pragma unroll
                    for (int j = 0; j < 4; ++j) {
                        uint2 pk;
                        pk.x = cvt_pk_bf16(s[i][j][0], s[i][j][1]);
                        pk.y = cvt_pk_bf16(s[i][j][2], s[i][j][3]);
                        *(s16x4*)&pl[(i * 16 + lr) * 72 + j * 16 + lc * 4] =
                            __builtin_bit_cast(s16x4, pk);
                    }
                }
                // PV: A = P rows q (private LDS), B = V^T frags (shared LDS)
                s16x8 aP[2][2];
                #pragma unroll
                for (int i = 0; i < 2; ++i)
                    #pragma unroll
                    for (int kk = 0; kk < 2; ++kk)
                        aP[i][kk] = *(const s16x8*)&pl[(i * 16 + lr) * 72 + kk * 32 + lc * 8];
                #pragma unroll
                for (int jd = 0; jd < 4; ++jd) {
                    s16x8 v0 = *(const s16x8*)&vtl[(jd * 2 + 0) * 512 + l * 8];
                    s16x8 v1 = *(const s16x8*)&vtl[(jd * 2 + 1) * 512 + l * 8];
                    O[0][jd] = mfma16(aP[0][0], v0, O[0][jd]);
                    O[0][jd] = mfma16(aP[0][1], v1, O[0][jd]);
                    O[1][jd] = mfma16(aP[1][0], v0, O[1][jd]);
                    O[1][jd] = mfma16(aP[1][1], v1, O[1][jd]);
                }
            }
        }

        // finalize: reduce ls across lc groups (q row = lr), invert, redistribute
        float lsr[2];
        #pragma unroll
        for (int i = 0; i < 2; ++i) {
            float t2 = (lsv[i][0] + lsv[i][1]) + (lsv[i][2] + lsv[i][3]);
            t2 += __shfl_xor(t2, 16);
            t2 += __shfl_xor(t2, 32);
            lsr[i] = 1.0f / t2;
        }
        float inv[2][4];
        #pragma unroll
        for (int i = 0; i < 2; ++i)
            #pragma unroll
            for (int r = 0; r < 4; ++r)
                inv[i][r] = __shfl(lsr[i], lc * 4 + r);

        #pragma unroll
        for (int i = 0; i < 2; ++i)
            #pragma unroll
            for (int jd = 0; jd < 4; ++jd)
                #pragma unroll
                for (int r = 0; r < 4; ++r) {
                    const int srow = q0 + i * 16 + lc * 4 + r;
                    ao[((size_t)(bb * 2048 + srow)) * 1024 + h * 64 + jd * 16 + lr] =
                        f2bf(O[i][jd][r] * inv[i][r]);
                }
    }
}

// ---------------- output projection GEMM (r3 known-good structure) ----------------
__global__ __launch_bounds__(256) void gemm_out(
    const u16* __restrict__ A, const u16* __restrict__ B,
    const float* __restrict__ bias, float* __restrict__ out)
{
    __shared__ u16 As[128 * 32];
    __shared__ u16 Bs[128 * 32];
    const int tid = threadIdx.x;
    const int w = tid >> 6, l = tid & 63;
    const int lr = l & 15, lc = l >> 4;
    const int m0 = blockIdx.x * 128, n0 = blockIdx.y * 128;
    const int wm = (w >> 1) * 64, wn = (w & 1) * 64;

    const int srow = w * 32 + (l >> 2);
    const int scol = (l & 3) * 8;
    const u16* gA = A + (size_t)(m0 + srow) * K_DIM + scol;
    const u16* gB = B + (size_t)(n0 + srow) * K_DIM + scol;
    u16* lA = &As[w * 1024];
    u16* lB = &Bs[w * 1024];

    f32x4 acc[4][4] = {};

    for (int k0 = 0; k0 < K_DIM; k0 += 32) {
        __syncthreads();
        gload16(gA + k0, lA);
        gload16(gA + 16 * K_DIM + k0, lA + 512);
        gload16(gB + k0, lB);
        gload16(gB + 16 * K_DIM + k0, lB + 512);
        __syncthreads();
        s16x8 a[4], b[4];
        #pragma unroll
        for (int i = 0; i < 4; ++i)
            a[i] = *(const s16x8*)&As[(wm + i * 16 + lr) * 32 + lc * 8];
        #pragma unroll
        for (int j = 0; j < 4; ++j)
            b[j] = *(const s16x8*)&Bs[(wn + j * 16 + lr) * 32 + lc * 8];
        #pragma unroll
        for (int i = 0; i < 4; ++i)
            #pragma unroll
            for (int j = 0; j < 4; ++j)
                acc[i][j] = mfma16(a[i], b[j], acc[i][j]);
    }

    #pragma unroll
    for (int j = 0; j < 4; ++j) {
        const int n = n0 + wn + j * 16 + lr;
        const float bv = bias[n];
        #pragma unroll
        for (int i = 0; i < 4; ++i) {
            #pragma unroll
            for (int r = 0; r < 4; ++r) {
                const int m = m0 + wm + i * 16 + lc * 4 + r;
                out[(size_t)m * 1024 + n] = acc[i][j][r] + bv;
            }
        }
    }
}

// ---------------- launcher ----------------
extern "C" void kernel_launch(void* const* d_in, const int* in_sizes, int n_in,
                              void* d_out, int out_size, void* d_ws, size_t ws_size,
                              hipStream_t stream) {
    const float* x     = (const float*)d_in[0];
    const float* w_qkv = (const float*)d_in[1];
    const float* b_qkv = (const float*)d_in[2];
    const float* w_out = (const float*)d_in[3];
    const float* b_out = (const float*)d_in[4];
    float* out = (float*)d_out;

    char* ws = (char*)d_ws;
    u16* xb   = (u16*)(ws);                    // 8192x1024 bf16  (16 MB)
    u16* wqb  = (u16*)(ws + 16777216);         // 3072x1024 bf16  (6 MB)
    u16* wob  = (u16*)(ws + 23068672);         // 1024x1024 bf16  (2 MB)
    u16* qws  = (u16*)(ws + 25165824);         // [64][2048][64]  (16 MB)
    u16* kws  = (u16*)(ws + 41943040);         // [64][2048][64]  (16 MB)
    u16* vtws = (u16*)(ws + 58720256);         // [64][64][2048]  (16 MB)
    u16* attn = (u16*)(ws + 75497472);         // 8192x1024 bf16  (16 MB)

    cvt_f2bf<<<dim3(2048), 256, 0, stream>>>(x,     xb,  8388608 / 4);
    cvt_f2bf<<<dim3(2048), 256, 0, stream>>>(w_qkv, wqb, 3145728 / 4);
    cvt_f2bf<<<dim3(1024), 256, 0, stream>>>(w_out, wob, 1048576 / 4);

    gemm_qkv<<<dim3(64, 24), 256, 0, stream>>>(xb, wqb, b_qkv, qws, kws, vtws);
    attn_fwd<<<dim3(64, 8), 256, 0, stream>>>(qws, kws, vtws, attn);
    gemm_out<<<dim3(64, 8), 256, 0, stream>>>(attn, wob, b_out, out);
}

// Round 10
// 171.273 us; speedup vs baseline: 2.0754x; 1.0703x over previous
//
#include <hip/hip_runtime.h>
#include <stdint.h>

typedef __bf16 bf16x8 __attribute__((ext_vector_type(8)));
typedef short s16x8 __attribute__((ext_vector_type(8)));
typedef short s16x4 __attribute__((ext_vector_type(4)));
typedef float f32x4 __attribute__((ext_vector_type(4)));
typedef unsigned short u16;

#define K_DIM 1024

static __device__ __forceinline__ u16 f2bf(float f) {
    uint32_t x = __float_as_uint(f);
    x += 0x7fffu + ((x >> 16) & 1u);
    return (u16)(x >> 16);
}

static __device__ __forceinline__ f32x4 mfma16(s16x8 a, s16x8 b, f32x4 c) {
    return __builtin_amdgcn_mfma_f32_16x16x32_bf16(
        __builtin_bit_cast(bf16x8, a), __builtin_bit_cast(bf16x8, b), c, 0, 0, 0);
}

static __device__ __forceinline__ void gload16(const u16* g, u16* l) {
    __builtin_amdgcn_global_load_lds(
        (const __attribute__((address_space(1))) void*)g,
        (__attribute__((address_space(3))) void*)l,
        16, 0, 0);
}

static __device__ __forceinline__ uint32_t cvt_pk_bf16(float lo, float hi) {
    uint32_t r;
    asm("v_cvt_pk_bf16_f32 %0, %1, %2" : "=v"(r) : "v"(lo), "v"(hi));
    return r;
}

static __device__ __forceinline__ float fexp2(float x) {
#if __has_builtin(__builtin_amdgcn_exp2f)
    return __builtin_amdgcn_exp2f(x);
#else
    return __expf(x * 0.69314718056f);
#endif
}

// ---------------- fp32 -> bf16 conversion ----------------
__global__ void cvt_f2bf(const float* __restrict__ in, u16* __restrict__ out, int n4) {
    int stride = gridDim.x * blockDim.x;
    for (int i = blockIdx.x * blockDim.x + threadIdx.x; i < n4; i += stride) {
        float4 f = ((const float4*)in)[i];
        ushort4 o;
        o.x = f2bf(f.x); o.y = f2bf(f.y); o.z = f2bf(f.z); o.w = f2bf(f.w);
        ((ushort4*)out)[i] = o;
    }
}

// ---------------- QKV projection GEMM ----------------
// r3 K-loop structure + XCD swizzle + LDS-transposed epilogue for the V section
// (s-contiguous 16B stores instead of 16-lane x 4KB-stride 2B scatters).
__global__ __launch_bounds__(256) void gemm_qkv(
    const u16* __restrict__ A, const u16* __restrict__ B,
    const float* __restrict__ bias,
    u16* __restrict__ qo, u16* __restrict__ ko, u16* __restrict__ vto)
{
    __shared__ u16 As[128 * 32];
    __shared__ u16 Bs[128 * 32];
    __shared__ u16 ct[32 * 136];      // V-epilogue transpose tile (pad 136: 16B-aligned rows)
    const int tid = threadIdx.x;
    const int w = tid >> 6, l = tid & 63;
    const int lr = l & 15, lc = l >> 4;

    // XCD-aware bijective swizzle (nwg = 1536, %8==0): within-XCD blocks are
    // m-consecutive at fixed n -> shared w_qkv panel stays in that XCD's L2.
    const int flat = blockIdx.y * 64 + blockIdx.x;
    const int swz = (flat & 7) * 192 + (flat >> 3);
    const int m0 = (swz & 63) * 128, n0 = (swz >> 6) * 128;
    const int wm = (w >> 1) * 64, wn = (w & 1) * 64;

    const int srow = w * 32 + (l >> 2);
    const int scol = (l & 3) * 8;
    const u16* gA = A + (size_t)(m0 + srow) * K_DIM + scol;
    const u16* gB = B + (size_t)(n0 + srow) * K_DIM + scol;
    u16* lA = &As[w * 1024];
    u16* lB = &Bs[w * 1024];

    f32x4 acc[4][4] = {};

    for (int k0 = 0; k0 < K_DIM; k0 += 32) {
        __syncthreads();
        gload16(gA + k0, lA);
        gload16(gA + 16 * K_DIM + k0, lA + 512);
        gload16(gB + k0, lB);
        gload16(gB + 16 * K_DIM + k0, lB + 512);
        __syncthreads();
        s16x8 a[4], b[4];
        #pragma unroll
        for (int i = 0; i < 4; ++i)
            a[i] = *(const s16x8*)&As[(wm + i * 16 + lr) * 32 + lc * 8];
        #pragma unroll
        for (int j = 0; j < 4; ++j)
            b[j] = *(const s16x8*)&Bs[(wn + j * 16 + lr) * 32 + lc * 8];
        #pragma unroll
        for (int i = 0; i < 4; ++i)
            #pragma unroll
            for (int j = 0; j < 4; ++j)
                acc[i][j] = mfma16(a[i], b[j], acc[i][j]);
    }

    const int sec = n0 >> 10;   // block-uniform: n-blocks 128-wide, sections 1024-aligned
    const int bb = m0 >> 11, s0 = m0 & 2047;

    if (sec < 2) {
        // q / k: direct stores (d across lanes -> 32B chunks, cacheline-friendly)
        #pragma unroll
        for (int j = 0; j < 4; ++j) {
            const int n = n0 + wn + j * 16 + lr;
            const float bv = bias[n];
            const int h = (n & 1023) >> 6, d = n & 63;
            #pragma unroll
            for (int i = 0; i < 4; ++i) {
                #pragma unroll
                for (int r = 0; r < 4; ++r) {
                    const int m = m0 + wm + i * 16 + lc * 4 + r;
                    const int s = m & 2047;
                    float v = acc[i][j][r] + bv;
                    if (sec == 0)
                        qo[((size_t)((bb * 16 + h) * 2048 + s)) * 64 + d] = f2bf(v * 0.18033688f);
                    else
                        ko[((size_t)((bb * 16 + h) * 2048 + s)) * 64 + d] = f2bf(v);
                }
            }
        }
    } else {
        // V: transpose 16-col groups through LDS, store s-contiguous 16B runs
        #pragma unroll
        for (int jj = 0; jj < 4; ++jj) {
            const int nl = (wn >> 6) * 16 + lr;           // 0..31 (w0/w2 -> lr, w1/w3 -> 16+lr)
            const float bv = bias[n0 + wn + jj * 16 + lr];
            #pragma unroll
            for (int i = 0; i < 4; ++i) {
                const int mloc = wm + i * 16 + lc * 4;    // m halves: w0/w1 0..63, w2/w3 64..127
                uint2 pk;
                pk.x = cvt_pk_bf16(acc[i][jj][0] + bv, acc[i][jj][1] + bv);
                pk.y = cvt_pk_bf16(acc[i][jj][2] + bv, acc[i][jj][3] + bv);
                *(s16x4*)&ct[nl * 136 + mloc] = __builtin_bit_cast(s16x4, pk);
            }
            __syncthreads();
            #pragma unroll
            for (int rep = 0; rep < 2; ++rep) {
                const int col = tid >> 3;                 // 0..31
                const int seg = (tid & 7) + rep * 8;      // 0..15
                const int nn = n0 + (col >> 4) * 64 + jj * 16 + (col & 15);
                const int h = (nn & 1023) >> 6, d = nn & 63;
                const int mo = seg * 8;
                s16x8 v = *(const s16x8*)&ct[col * 136 + mo];
                *(s16x8*)&vto[((size_t)((bb * 16 + h) * 64 + d)) * 2048 + s0 + mo] = v;
            }
            __syncthreads();
        }
    }
}

// ---------------- flash attention (causal, static-max, swapped QK^T) ----------------
// r9 known-good: block = 128 q-rows of one head (4 waves x QBLK=32), chunk pair
// (C, 15-C) -> 34 kv-iterations/block; K/V tiles staged to LDS fragment-major
// via global_load_lds and shared by the 4 waves (4x global traffic reduction).
__global__ __launch_bounds__(256, 2) void attn_fwd(
    const u16* __restrict__ q, const u16* __restrict__ k,
    const u16* __restrict__ vt, u16* __restrict__ ao)
{
    __shared__ u16 kt[8 * 512];
    __shared__ u16 vtl[8 * 512];
    __shared__ u16 plds[4 * 32 * 72];
    const int w = threadIdx.x >> 6, l = threadIdx.x & 63;
    const int lr = l & 15, lc = l >> 4;
    const int bh = blockIdx.x;
    const int cp = blockIdx.y;
    const u16* qp = q + (size_t)bh * 2048 * 64;
    const u16* kp = k + (size_t)bh * 2048 * 64;
    const u16* vp = vt + (size_t)bh * 64 * 2048;
    u16* pl = &plds[w * 2304];
    const int bb = bh >> 4, h = bh & 15;

    for (int pass = 0; pass < 2; ++pass) {
        const int C = pass ? (15 - cp) : cp;
        const int q0 = C * 128 + w * 32;
        const int nb = 2 * C + 2;
        const int diag = 2 * C + (w >> 1);

        s16x8 aQ[2][2];
        #pragma unroll
        for (int i = 0; i < 2; ++i)
            #pragma unroll
            for (int kk = 0; kk < 2; ++kk)
                aQ[i][kk] = *(const s16x8*)&qp[(q0 + i * 16 + lr) * 64 + kk * 32 + lc * 8];

        f32x4 O[2][4] = {};
        f32x4 lsv[2] = {};

        for (int t = 0; t < nb; ++t) {
            const int c0 = t * 64;
            __syncthreads();
            if (w < 2) {
                #pragma unroll
                for (int gi = 0; gi < 4; ++gi) {
                    const int g = w * 4 + gi;
                    const int j = g >> 1, kk = g & 1;
                    gload16(kp + (c0 + j * 16 + lr) * 64 + kk * 32 + lc * 8, &kt[g * 512]);
                }
            } else {
                #pragma unroll
                for (int gi = 0; gi < 4; ++gi) {
                    const int g = (w - 2) * 4 + gi;
                    const int jd = g >> 1, kk = g & 1;
                    gload16(vp + (jd * 16 + lr) * 2048 + c0 + kk * 32 + lc * 8, &vtl[g * 512]);
                }
            }
            __syncthreads();

            if (t <= diag) {
                f32x4 s[2][4] = {};
                #pragma unroll
                for (int j = 0; j < 4; ++j) {
                    s16x8 k0 = *(const s16x8*)&kt[(j * 2 + 0) * 512 + l * 8];
                    s16x8 k1 = *(const s16x8*)&kt[(j * 2 + 1) * 512 + l * 8];
                    s[0][j] = mfma16(k0, aQ[0][0], s[0][j]);
                    s[0][j] = mfma16(k1, aQ[0][1], s[0][j]);
                    s[1][j] = mfma16(k0, aQ[1][0], s[1][j]);
                    s[1][j] = mfma16(k1, aQ[1][1], s[1][j]);
                }
                if (t == diag) {
                    #pragma unroll
                    for (int i = 0; i < 2; ++i) {
                        const int qrow = q0 + i * 16 + lr;
                        #pragma unroll
                        for (int j = 0; j < 4; ++j) {
                            const int kvb = c0 + j * 16 + lc * 4;
                            #pragma unroll
                            for (int r = 0; r < 4; ++r)
                                if (kvb + r > qrow) s[i][j][r] = -1e30f;
                        }
                    }
                }
                #pragma unroll
                for (int i = 0; i < 2; ++i) {
                    #pragma unroll
                    for (int j = 0; j < 4; ++j)
                        #pragma unroll
                        for (int r = 0; r < 4; ++r)
                            s[i][j][r] = fexp2(s[i][j][r]);
                    lsv[i] += (s[i][0] + s[i][1]) + (s[i][2] + s[i][3]);
                    #pragma unroll
                    for (int j = 0; j < 4; ++j) {
                        uint2 pk;
                        pk.x = cvt_pk_bf16(s[i][j][0], s[i][j][1]);
                        pk.y = cvt_pk_bf16(s[i][j][2], s[i][j][3]);
                        *(s16x4*)&pl[(i * 16 + lr) * 72 + j * 16 + lc * 4] =
                            __builtin_bit_cast(s16x4, pk);
                    }
                }
                s16x8 aP[2][2];
                #pragma unroll
                for (int i = 0; i < 2; ++i)
                    #pragma unroll
                    for (int kk = 0; kk < 2; ++kk)
                        aP[i][kk] = *(const s16x8*)&pl[(i * 16 + lr) * 72 + kk * 32 + lc * 8];
                #pragma unroll
                for (int jd = 0; jd < 4; ++jd) {
                    s16x8 v0 = *(const s16x8*)&vtl[(jd * 2 + 0) * 512 + l * 8];
                    s16x8 v1 = *(const s16x8*)&vtl[(jd * 2 + 1) * 512 + l * 8];
                    O[0][jd] = mfma16(aP[0][0], v0, O[0][jd]);
                    O[0][jd] = mfma16(aP[0][1], v1, O[0][jd]);
                    O[1][jd] = mfma16(aP[1][0], v0, O[1][jd]);
                    O[1][jd] = mfma16(aP[1][1], v1, O[1][jd]);
                }
            }
        }

        float lsr[2];
        #pragma unroll
        for (int i = 0; i < 2; ++i) {
            float t2 = (lsv[i][0] + lsv[i][1]) + (lsv[i][2] + lsv[i][3]);
            t2 += __shfl_xor(t2, 16);
            t2 += __shfl_xor(t2, 32);
            lsr[i] = 1.0f / t2;
        }
        float inv[2][4];
        #pragma unroll
        for (int i = 0; i < 2; ++i)
            #pragma unroll
            for (int r = 0; r < 4; ++r)
                inv[i][r] = __shfl(lsr[i], lc * 4 + r);

        #pragma unroll
        for (int i = 0; i < 2; ++i)
            #pragma unroll
            for (int jd = 0; jd < 4; ++jd)
                #pragma unroll
                for (int r = 0; r < 4; ++r) {
                    const int srow = q0 + i * 16 + lc * 4 + r;
                    ao[((size_t)(bb * 2048 + srow)) * 1024 + h * 64 + jd * 16 + lr] =
                        f2bf(O[i][jd][r] * inv[i][r]);
                }
    }
}

// ---------------- output projection GEMM (r3 known-good structure) ----------------
__global__ __launch_bounds__(256) void gemm_out(
    const u16* __restrict__ A, const u16* __restrict__ B,
    const float* __restrict__ bias, float* __restrict__ out)
{
    __shared__ u16 As[128 * 32];
    __shared__ u16 Bs[128 * 32];
    const int tid = threadIdx.x;
    const int w = tid >> 6, l = tid & 63;
    const int lr = l & 15, lc = l >> 4;
    const int m0 = blockIdx.x * 128, n0 = blockIdx.y * 128;
    const int wm = (w >> 1) * 64, wn = (w & 1) * 64;

    const int srow = w * 32 + (l >> 2);
    const int scol = (l & 3) * 8;
    const u16* gA = A + (size_t)(m0 + srow) * K_DIM + scol;
    const u16* gB = B + (size_t)(n0 + srow) * K_DIM + scol;
    u16* lA = &As[w * 1024];
    u16* lB = &Bs[w * 1024];

    f32x4 acc[4][4] = {};

    for (int k0 = 0; k0 < K_DIM; k0 += 32) {
        __syncthreads();
        gload16(gA + k0, lA);
        gload16(gA + 16 * K_DIM + k0, lA + 512);
        gload16(gB + k0, lB);
        gload16(gB + 16 * K_DIM + k0, lB + 512);
        __syncthreads();
        s16x8 a[4], b[4];
        #pragma unroll
        for (int i = 0; i < 4; ++i)
            a[i] = *(const s16x8*)&As[(wm + i * 16 + lr) * 32 + lc * 8];
        #pragma unroll
        for (int j = 0; j < 4; ++j)
            b[j] = *(const s16x8*)&Bs[(wn + j * 16 + lr) * 32 + lc * 8];
        #pragma unroll
        for (int i = 0; i < 4; ++i)
            #pragma unroll
            for (int j = 0; j < 4; ++j)
                acc[i][j] = mfma16(a[i], b[j], acc[i][j]);
    }

    #pragma unroll
    for (int j = 0; j < 4; ++j) {
        const int n = n0 + wn + j * 16 + lr;
        const float bv = bias[n];
        #pragma unroll
        for (int i = 0; i < 4; ++i) {
            #pragma unroll
            for (int r = 0; r < 4; ++r) {
                const int m = m0 + wm + i * 16 + lc * 4 + r;
                out[(size_t)m * 1024 + n] = acc[i][j][r] + bv;
            }
        }
    }
}

// ---------------- launcher ----------------
extern "C" void kernel_launch(void* const* d_in, const int* in_sizes, int n_in,
                              void* d_out, int out_size, void* d_ws, size_t ws_size,
                              hipStream_t stream) {
    const float* x     = (const float*)d_in[0];
    const float* w_qkv = (const float*)d_in[1];
    const float* b_qkv = (const float*)d_in[2];
    const float* w_out = (const float*)d_in[3];
    const float* b_out = (const float*)d_in[4];
    float* out = (float*)d_out;

    char* ws = (char*)d_ws;
    u16* xb   = (u16*)(ws);                    // 8192x1024 bf16  (16 MB)
    u16* wqb  = (u16*)(ws + 16777216);         // 3072x1024 bf16  (6 MB)
    u16* wob  = (u16*)(ws + 23068672);         // 1024x1024 bf16  (2 MB)
    u16* qws  = (u16*)(ws + 25165824);         // [64][2048][64]  (16 MB)
    u16* kws  = (u16*)(ws + 41943040);         // [64][2048][64]  (16 MB)
    u16* vtws = (u16*)(ws + 58720256);         // [64][64][2048]  (16 MB)
    u16* attn = (u16*)(ws + 75497472);         // 8192x1024 bf16  (16 MB)

    cvt_f2bf<<<dim3(2048), 256, 0, stream>>>(x,     xb,  8388608 / 4);
    cvt_f2bf<<<dim3(2048), 256, 0, stream>>>(w_qkv, wqb, 3145728 / 4);
    cvt_f2bf<<<dim3(1024), 256, 0, stream>>>(w_out, wob, 1048576 / 4);

    gemm_qkv<<<dim3(64, 24), 256, 0, stream>>>(xb, wqb, b_qkv, qws, kws, vtws);
    attn_fwd<<<dim3(64, 8), 256, 0, stream>>>(qws, kws, vtws, attn);
    gemm_out<<<dim3(64, 8), 256, 0, stream>>>(attn, wob, b_out, out);
}

// Round 11
// 163.655 us; speedup vs baseline: 2.1720x; 1.0465x over previous
//
#include <hip/hip_runtime.h>
#include <stdint.h>

typedef __bf16 bf16x8 __attribute__((ext_vector_type(8)));
typedef short s16x8 __attribute__((ext_vector_type(8)));
typedef short s16x4 __attribute__((ext_vector_type(4)));
typedef float f32x4 __attribute__((ext_vector_type(4)));
typedef unsigned short u16;

#define K_DIM 1024

static __device__ __forceinline__ u16 f2bf(float f) {
    uint32_t x = __float_as_uint(f);
    x += 0x7fffu + ((x >> 16) & 1u);
    return (u16)(x >> 16);
}

static __device__ __forceinline__ f32x4 mfma16(s16x8 a, s16x8 b, f32x4 c) {
    return __builtin_amdgcn_mfma_f32_16x16x32_bf16(
        __builtin_bit_cast(bf16x8, a), __builtin_bit_cast(bf16x8, b), c, 0, 0, 0);
}

static __device__ __forceinline__ void gload16(const u16* g, u16* l) {
    __builtin_amdgcn_global_load_lds(
        (const __attribute__((address_space(1))) void*)g,
        (__attribute__((address_space(3))) void*)l,
        16, 0, 0);
}

static __device__ __forceinline__ uint32_t cvt_pk_bf16(float lo, float hi) {
    uint32_t r;
    asm("v_cvt_pk_bf16_f32 %0, %1, %2" : "=v"(r) : "v"(lo), "v"(hi));
    return r;
}

static __device__ __forceinline__ float fexp2(float x) {
#if __has_builtin(__builtin_amdgcn_exp2f)
    return __builtin_amdgcn_exp2f(x);
#else
    return __expf(x * 0.69314718056f);
#endif
}

// ---------------- fp32 -> bf16 conversion ----------------
__global__ void cvt_f2bf(const float* __restrict__ in, u16* __restrict__ out, int n4) {
    int stride = gridDim.x * blockDim.x;
    for (int i = blockIdx.x * blockDim.x + threadIdx.x; i < n4; i += stride) {
        float4 f = ((const float4*)in)[i];
        ushort4 o;
        o.x = f2bf(f.x); o.y = f2bf(f.y); o.z = f2bf(f.z); o.w = f2bf(f.w);
        ((ushort4*)out)[i] = o;
    }
}

// ---------------- QKV projection GEMM ----------------
// Natural block mapping (blockIdx.x = m fast -> XCD = m-block mod 8: each XCD
// reads 8 A-panels x all n; A fetched once chip-wide). LDS-transposed V epilogue.
__global__ __launch_bounds__(256) void gemm_qkv(
    const u16* __restrict__ A, const u16* __restrict__ B,
    const float* __restrict__ bias,
    u16* __restrict__ qo, u16* __restrict__ ko, u16* __restrict__ vto)
{
    __shared__ u16 As[128 * 32];
    __shared__ u16 Bs[128 * 32];
    __shared__ u16 ct[32 * 136];      // V-epilogue transpose tile
    const int tid = threadIdx.x;
    const int w = tid >> 6, l = tid & 63;
    const int lr = l & 15, lc = l >> 4;
    const int m0 = blockIdx.x * 128, n0 = blockIdx.y * 128;
    const int wm = (w >> 1) * 64, wn = (w & 1) * 64;

    const int srow = w * 32 + (l >> 2);
    const int scol = (l & 3) * 8;
    const u16* gA = A + (size_t)(m0 + srow) * K_DIM + scol;
    const u16* gB = B + (size_t)(n0 + srow) * K_DIM + scol;
    u16* lA = &As[w * 1024];
    u16* lB = &Bs[w * 1024];

    f32x4 acc[4][4] = {};

    for (int k0 = 0; k0 < K_DIM; k0 += 32) {
        __syncthreads();
        gload16(gA + k0, lA);
        gload16(gA + 16 * K_DIM + k0, lA + 512);
        gload16(gB + k0, lB);
        gload16(gB + 16 * K_DIM + k0, lB + 512);
        __syncthreads();
        s16x8 a[4], b[4];
        #pragma unroll
        for (int i = 0; i < 4; ++i)
            a[i] = *(const s16x8*)&As[(wm + i * 16 + lr) * 32 + lc * 8];
        #pragma unroll
        for (int j = 0; j < 4; ++j)
            b[j] = *(const s16x8*)&Bs[(wn + j * 16 + lr) * 32 + lc * 8];
        #pragma unroll
        for (int i = 0; i < 4; ++i)
            #pragma unroll
            for (int j = 0; j < 4; ++j)
                acc[i][j] = mfma16(a[i], b[j], acc[i][j]);
    }

    const int sec = n0 >> 10;   // block-uniform
    const int bb = m0 >> 11, s0 = m0 & 2047;

    if (sec < 2) {
        #pragma unroll
        for (int j = 0; j < 4; ++j) {
            const int n = n0 + wn + j * 16 + lr;
            const float bv = bias[n];
            const int h = (n & 1023) >> 6, d = n & 63;
            #pragma unroll
            for (int i = 0; i < 4; ++i) {
                #pragma unroll
                for (int r = 0; r < 4; ++r) {
                    const int m = m0 + wm + i * 16 + lc * 4 + r;
                    const int s = m & 2047;
                    float v = acc[i][j][r] + bv;
                    if (sec == 0)
                        qo[((size_t)((bb * 16 + h) * 2048 + s)) * 64 + d] = f2bf(v * 0.18033688f);
                    else
                        ko[((size_t)((bb * 16 + h) * 2048 + s)) * 64 + d] = f2bf(v);
                }
            }
        }
    } else {
        // V: transpose 16-col groups through LDS, store s-contiguous 16B runs
        #pragma unroll
        for (int jj = 0; jj < 4; ++jj) {
            const int nl = (wn >> 6) * 16 + lr;
            const float bv = bias[n0 + wn + jj * 16 + lr];
            #pragma unroll
            for (int i = 0; i < 4; ++i) {
                const int mloc = wm + i * 16 + lc * 4;
                uint2 pk;
                pk.x = cvt_pk_bf16(acc[i][jj][0] + bv, acc[i][jj][1] + bv);
                pk.y = cvt_pk_bf16(acc[i][jj][2] + bv, acc[i][jj][3] + bv);
                *(s16x4*)&ct[nl * 136 + mloc] = __builtin_bit_cast(s16x4, pk);
            }
            __syncthreads();
            #pragma unroll
            for (int rep = 0; rep < 2; ++rep) {
                const int col = tid >> 3;
                const int seg = (tid & 7) + rep * 8;
                const int nn = n0 + (col >> 4) * 64 + jj * 16 + (col & 15);
                const int h = (nn & 1023) >> 6, d = nn & 63;
                const int mo = seg * 8;
                s16x8 v = *(const s16x8*)&ct[col * 136 + mo];
                *(s16x8*)&vto[((size_t)((bb * 16 + h) * 64 + d)) * 2048 + s0 + mo] = v;
            }
            __syncthreads();
        }
    }
}

// ---------------- flash attention (causal, static-max, swapped QK^T) ----------------
// r9 structure + DOUBLE-BUFFERED K/V staging (2-phase pipeline): tile t+1's
// global_load_lds are issued before computing tile t; the next iteration's
// barrier drains them. Staging latency hides under QK/softmax/PV.
__global__ __launch_bounds__(256, 2) void attn_fwd(
    const u16* __restrict__ q, const u16* __restrict__ k,
    const u16* __restrict__ vt, u16* __restrict__ ao)
{
    __shared__ u16 kt[2][8 * 512];
    __shared__ u16 vtl[2][8 * 512];
    __shared__ u16 plds[4 * 32 * 72];
    const int w = threadIdx.x >> 6, l = threadIdx.x & 63;
    const int lr = l & 15, lc = l >> 4;
    const int bh = blockIdx.x;
    const int cp = blockIdx.y;
    const u16* qp = q + (size_t)bh * 2048 * 64;
    const u16* kp = k + (size_t)bh * 2048 * 64;
    const u16* vp = vt + (size_t)bh * 64 * 2048;
    u16* pl = &plds[w * 2304];
    const int bb = bh >> 4, h = bh & 15;

    for (int pass = 0; pass < 2; ++pass) {
        const int C = pass ? (15 - cp) : cp;
        const int q0 = C * 128 + w * 32;
        const int nb = 2 * C + 2;
        const int diag = 2 * C + (w >> 1);

        s16x8 aQ[2][2];
        #pragma unroll
        for (int i = 0; i < 2; ++i)
            #pragma unroll
            for (int kk = 0; kk < 2; ++kk)
                aQ[i][kk] = *(const s16x8*)&qp[(q0 + i * 16 + lr) * 64 + kk * 32 + lc * 8];

        f32x4 O[2][4] = {};
        f32x4 lsv[2] = {};

        auto stage = [&](int t, int buf) {
            const int c0 = t * 64;
            if (w < 2) {
                #pragma unroll
                for (int gi = 0; gi < 4; ++gi) {
                    const int g = w * 4 + gi;
                    const int j = g >> 1, kk = g & 1;
                    gload16(kp + (c0 + j * 16 + lr) * 64 + kk * 32 + lc * 8,
                            &kt[buf][g * 512]);
                }
            } else {
                #pragma unroll
                for (int gi = 0; gi < 4; ++gi) {
                    const int g = (w - 2) * 4 + gi;
                    const int jd = g >> 1, kk = g & 1;
                    gload16(vp + (jd * 16 + lr) * 2048 + c0 + kk * 32 + lc * 8,
                            &vtl[buf][g * 512]);
                }
            }
        };

        __syncthreads();            // prev pass's tile reads done (buffers reusable)
        stage(0, 0);
        int cur = 0;

        for (int t = 0; t < nb; ++t) {
            __syncthreads();        // buf[cur] staging drained (vmcnt(0) at barrier)
            if (t + 1 < nb) stage(t + 1, cur ^ 1);   // async prefetch, overlaps compute

            if (t <= diag) {
                const int c0 = t * 64;
                f32x4 s[2][4] = {};
                #pragma unroll
                for (int j = 0; j < 4; ++j) {
                    s16x8 k0 = *(const s16x8*)&kt[cur][(j * 2 + 0) * 512 + l * 8];
                    s16x8 k1 = *(const s16x8*)&kt[cur][(j * 2 + 1) * 512 + l * 8];
                    s[0][j] = mfma16(k0, aQ[0][0], s[0][j]);
                    s[0][j] = mfma16(k1, aQ[0][1], s[0][j]);
                    s[1][j] = mfma16(k0, aQ[1][0], s[1][j]);
                    s[1][j] = mfma16(k1, aQ[1][1], s[1][j]);
                }
                if (t == diag) {
                    #pragma unroll
                    for (int i = 0; i < 2; ++i) {
                        const int qrow = q0 + i * 16 + lr;
                        #pragma unroll
                        for (int j = 0; j < 4; ++j) {
                            const int kvb = c0 + j * 16 + lc * 4;
                            #pragma unroll
                            for (int r = 0; r < 4; ++r)
                                if (kvb + r > qrow) s[i][j][r] = -1e30f;
                        }
                    }
                }
                #pragma unroll
                for (int i = 0; i < 2; ++i) {
                    #pragma unroll
                    for (int j = 0; j < 4; ++j)
                        #pragma unroll
                        for (int r = 0; r < 4; ++r)
                            s[i][j][r] = fexp2(s[i][j][r]);
                    lsv[i] += (s[i][0] + s[i][1]) + (s[i][2] + s[i][3]);
                    #pragma unroll
                    for (int j = 0; j < 4; ++j) {
                        uint2 pk;
                        pk.x = cvt_pk_bf16(s[i][j][0], s[i][j][1]);
                        pk.y = cvt_pk_bf16(s[i][j][2], s[i][j][3]);
                        *(s16x4*)&pl[(i * 16 + lr) * 72 + j * 16 + lc * 4] =
                            __builtin_bit_cast(s16x4, pk);
                    }
                }
                s16x8 aP[2][2];
                #pragma unroll
                for (int i = 0; i < 2; ++i)
                    #pragma unroll
                    for (int kk = 0; kk < 2; ++kk)
                        aP[i][kk] = *(const s16x8*)&pl[(i * 16 + lr) * 72 + kk * 32 + lc * 8];
                #pragma unroll
                for (int jd = 0; jd < 4; ++jd) {
                    s16x8 v0 = *(const s16x8*)&vtl[cur][(jd * 2 + 0) * 512 + l * 8];
                    s16x8 v1 = *(const s16x8*)&vtl[cur][(jd * 2 + 1) * 512 + l * 8];
                    O[0][jd] = mfma16(aP[0][0], v0, O[0][jd]);
                    O[0][jd] = mfma16(aP[0][1], v1, O[0][jd]);
                    O[1][jd] = mfma16(aP[1][0], v0, O[1][jd]);
                    O[1][jd] = mfma16(aP[1][1], v1, O[1][jd]);
                }
            }
            cur ^= 1;
        }

        float lsr[2];
        #pragma unroll
        for (int i = 0; i < 2; ++i) {
            float t2 = (lsv[i][0] + lsv[i][1]) + (lsv[i][2] + lsv[i][3]);
            t2 += __shfl_xor(t2, 16);
            t2 += __shfl_xor(t2, 32);
            lsr[i] = 1.0f / t2;
        }
        float inv[2][4];
        #pragma unroll
        for (int i = 0; i < 2; ++i)
            #pragma unroll
            for (int r = 0; r < 4; ++r)
                inv[i][r] = __shfl(lsr[i], lc * 4 + r);

        #pragma unroll
        for (int i = 0; i < 2; ++i)
            #pragma unroll
            for (int jd = 0; jd < 4; ++jd)
                #pragma unroll
                for (int r = 0; r < 4; ++r) {
                    const int srow = q0 + i * 16 + lc * 4 + r;
                    ao[((size_t)(bb * 2048 + srow)) * 1024 + h * 64 + jd * 16 + lr] =
                        f2bf(O[i][jd][r] * inv[i][r]);
                }
    }
}

// ---------------- output projection GEMM (r3 known-good structure) ----------------
__global__ __launch_bounds__(256) void gemm_out(
    const u16* __restrict__ A, const u16* __restrict__ B,
    const float* __restrict__ bias, float* __restrict__ out)
{
    __shared__ u16 As[128 * 32];
    __shared__ u16 Bs[128 * 32];
    const int tid = threadIdx.x;
    const int w = tid >> 6, l = tid & 63;
    const int lr = l & 15, lc = l >> 4;
    const int m0 = blockIdx.x * 128, n0 = blockIdx.y * 128;
    const int wm = (w >> 1) * 64, wn = (w & 1) * 64;

    const int srow = w * 32 + (l >> 2);
    const int scol = (l & 3) * 8;
    const u16* gA = A + (size_t)(m0 + srow) * K_DIM + scol;
    const u16* gB = B + (size_t)(n0 + srow) * K_DIM + scol;
    u16* lA = &As[w * 1024];
    u16* lB = &Bs[w * 1024];

    f32x4 acc[4][4] = {};

    for (int k0 = 0; k0 < K_DIM; k0 += 32) {
        __syncthreads();
        gload16(gA + k0, lA);
        gload16(gA + 16 * K_DIM + k0, lA + 512);
        gload16(gB + k0, lB);
        gload16(gB + 16 * K_DIM + k0, lB + 512);
        __syncthreads();
        s16x8 a[4], b[4];
        #pragma unroll
        for (int i = 0; i < 4; ++i)
            a[i] = *(const s16x8*)&As[(wm + i * 16 + lr) * 32 + lc * 8];
        #pragma unroll
        for (int j = 0; j < 4; ++j)
            b[j] = *(const s16x8*)&Bs[(wn + j * 16 + lr) * 32 + lc * 8];
        #pragma unroll
        for (int i = 0; i < 4; ++i)
            #pragma unroll
            for (int j = 0; j < 4; ++j)
                acc[i][j] = mfma16(a[i], b[j], acc[i][j]);
    }

    #pragma unroll
    for (int j = 0; j < 4; ++j) {
        const int n = n0 + wn + j * 16 + lr;
        const float bv = bias[n];
        #pragma unroll
        for (int i = 0; i < 4; ++i) {
            #pragma unroll
            for (int r = 0; r < 4; ++r) {
                const int m = m0 + wm + i * 16 + lc * 4 + r;
                out[(size_t)m * 1024 + n] = acc[i][j][r] + bv;
            }
        }
    }
}

// ---------------- launcher ----------------
extern "C" void kernel_launch(void* const* d_in, const int* in_sizes, int n_in,
                              void* d_out, int out_size, void* d_ws, size_t ws_size,
                              hipStream_t stream) {
    const float* x     = (const float*)d_in[0];
    const float* w_qkv = (const float*)d_in[1];
    const float* b_qkv = (const float*)d_in[2];
    const float* w_out = (const float*)d_in[3];
    const float* b_out = (const float*)d_in[4];
    float* out = (float*)d_out;

    char* ws = (char*)d_ws;
    u16* xb   = (u16*)(ws);                    // 8192x1024 bf16  (16 MB)
    u16* wqb  = (u16*)(ws + 16777216);         // 3072x1024 bf16  (6 MB)
    u16* wob  = (u16*)(ws + 23068672);         // 1024x1024 bf16  (2 MB)
    u16* qws  = (u16*)(ws + 25165824);         // [64][2048][64]  (16 MB)
    u16* kws  = (u16*)(ws + 41943040);         // [64][2048][64]  (16 MB)
    u16* vtws = (u16*)(ws + 58720256);         // [64][64][2048]  (16 MB)
    u16* attn = (u16*)(ws + 75497472);         // 8192x1024 bf16  (16 MB)

    cvt_f2bf<<<dim3(2048), 256, 0, stream>>>(x,     xb,  8388608 / 4);
    cvt_f2bf<<<dim3(2048), 256, 0, stream>>>(w_qkv, wqb, 3145728 / 4);
    cvt_f2bf<<<dim3(1024), 256, 0, stream>>>(w_out, wob, 1048576 / 4);

    gemm_qkv<<<dim3(64, 24), 256, 0, stream>>>(xb, wqb, b_qkv, qws, kws, vtws);
    attn_fwd<<<dim3(64, 8), 256, 0, stream>>>(qws, kws, vtws, attn);
    gemm_out<<<dim3(64, 8), 256, 0, stream>>>(attn, wob, b_out, out);
}

// Round 12
// 160.331 us; speedup vs baseline: 2.2170x; 1.0207x over previous
//
#include <hip/hip_runtime.h>
#include <stdint.h>

typedef __bf16 bf16x8 __attribute__((ext_vector_type(8)));
typedef short s16x8 __attribute__((ext_vector_type(8)));
typedef short s16x4 __attribute__((ext_vector_type(4)));
typedef float f32x4 __attribute__((ext_vector_type(4)));
typedef unsigned short u16;

#define K_DIM 1024

static __device__ __forceinline__ u16 f2bf(float f) {
    uint32_t x = __float_as_uint(f);
    x += 0x7fffu + ((x >> 16) & 1u);
    return (u16)(x >> 16);
}

static __device__ __forceinline__ f32x4 mfma16(s16x8 a, s16x8 b, f32x4 c) {
    return __builtin_amdgcn_mfma_f32_16x16x32_bf16(
        __builtin_bit_cast(bf16x8, a), __builtin_bit_cast(bf16x8, b), c, 0, 0, 0);
}

static __device__ __forceinline__ void gload16(const u16* g, u16* l) {
    __builtin_amdgcn_global_load_lds(
        (const __attribute__((address_space(1))) void*)g,
        (__attribute__((address_space(3))) void*)l,
        16, 0, 0);
}

static __device__ __forceinline__ uint32_t cvt_pk_bf16(float lo, float hi) {
    uint32_t r;
    asm("v_cvt_pk_bf16_f32 %0, %1, %2" : "=v"(r) : "v"(lo), "v"(hi));
    return r;
}

static __device__ __forceinline__ float fexp2(float x) {
#if __has_builtin(__builtin_amdgcn_exp2f)
    return __builtin_amdgcn_exp2f(x);
#else
    return __expf(x * 0.69314718056f);
#endif
}

// ---------------- fp32 -> bf16 conversion ----------------
__global__ void cvt_f2bf(const float* __restrict__ in, u16* __restrict__ out, int n4) {
    int stride = gridDim.x * blockDim.x;
    for (int i = blockIdx.x * blockDim.x + threadIdx.x; i < n4; i += stride) {
        float4 f = ((const float4*)in)[i];
        ushort4 o;
        o.x = f2bf(f.x); o.y = f2bf(f.y); o.z = f2bf(f.z); o.w = f2bf(f.w);
        ((ushort4*)out)[i] = o;
    }
}

// ---------------- QKV projection GEMM ----------------
// r10 XCD swizzle (proven faster: per-XCD B-panels L2-resident, A streams) +
// LDS-transposed V epilogue with ct ALIASED onto As/Bs (barrier-separated).
__global__ __launch_bounds__(256) void gemm_qkv(
    const u16* __restrict__ A, const u16* __restrict__ B,
    const float* __restrict__ bias,
    u16* __restrict__ qo, u16* __restrict__ ko, u16* __restrict__ vto)
{
    __shared__ u16 smem[8192];        // As[4096] | Bs[4096]; ct[4352] aliases after barrier
    u16* As = smem;
    u16* Bs = smem + 4096;
    u16* ct = smem;                   // V-epilogue transpose tile [32][136]
    const int tid = threadIdx.x;
    const int w = tid >> 6, l = tid & 63;
    const int lr = l & 15, lc = l >> 4;

    // XCD-aware bijective swizzle (nwg=1536): XCD c gets n-panels {3c,3c+1,3c+2}
    // (0.75MB B resident in its L2) x all m (A streams).
    const int flat = blockIdx.y * 64 + blockIdx.x;
    const int swz = (flat & 7) * 192 + (flat >> 3);
    const int m0 = (swz & 63) * 128, n0 = (swz >> 6) * 128;
    const int wm = (w >> 1) * 64, wn = (w & 1) * 64;

    const int srow = w * 32 + (l >> 2);
    const int scol = (l & 3) * 8;
    const u16* gA = A + (size_t)(m0 + srow) * K_DIM + scol;
    const u16* gB = B + (size_t)(n0 + srow) * K_DIM + scol;
    u16* lA = &As[w * 1024];
    u16* lB = &Bs[w * 1024];

    f32x4 acc[4][4] = {};

    for (int k0 = 0; k0 < K_DIM; k0 += 32) {
        __syncthreads();
        gload16(gA + k0, lA);
        gload16(gA + 16 * K_DIM + k0, lA + 512);
        gload16(gB + k0, lB);
        gload16(gB + 16 * K_DIM + k0, lB + 512);
        __syncthreads();
        s16x8 a[4], b[4];
        #pragma unroll
        for (int i = 0; i < 4; ++i)
            a[i] = *(const s16x8*)&As[(wm + i * 16 + lr) * 32 + lc * 8];
        #pragma unroll
        for (int j = 0; j < 4; ++j)
            b[j] = *(const s16x8*)&Bs[(wn + j * 16 + lr) * 32 + lc * 8];
        #pragma unroll
        for (int i = 0; i < 4; ++i)
            #pragma unroll
            for (int j = 0; j < 4; ++j)
                acc[i][j] = mfma16(a[i], b[j], acc[i][j]);
    }

    const int sec = n0 >> 10;   // block-uniform
    const int bb = m0 >> 11, s0 = m0 & 2047;

    if (sec < 2) {
        #pragma unroll
        for (int j = 0; j < 4; ++j) {
            const int n = n0 + wn + j * 16 + lr;
            const float bv = bias[n];
            const int h = (n & 1023) >> 6, d = n & 63;
            #pragma unroll
            for (int i = 0; i < 4; ++i) {
                #pragma unroll
                for (int r = 0; r < 4; ++r) {
                    const int m = m0 + wm + i * 16 + lc * 4 + r;
                    const int s = m & 2047;
                    float v = acc[i][j][r] + bv;
                    if (sec == 0)
                        qo[((size_t)((bb * 16 + h) * 2048 + s)) * 64 + d] = f2bf(v * 0.18033688f);
                    else
                        ko[((size_t)((bb * 16 + h) * 2048 + s)) * 64 + d] = f2bf(v);
                }
            }
        }
    } else {
        __syncthreads();          // all As/Bs reads done before ct aliases them
        // V: transpose 16-col groups through LDS, store s-contiguous 16B runs
        #pragma unroll
        for (int jj = 0; jj < 4; ++jj) {
            const int nl = (wn >> 6) * 16 + lr;
            const float bv = bias[n0 + wn + jj * 16 + lr];
            #pragma unroll
            for (int i = 0; i < 4; ++i) {
                const int mloc = wm + i * 16 + lc * 4;
                uint2 pk;
                pk.x = cvt_pk_bf16(acc[i][jj][0] + bv, acc[i][jj][1] + bv);
                pk.y = cvt_pk_bf16(acc[i][jj][2] + bv, acc[i][jj][3] + bv);
                *(s16x4*)&ct[nl * 136 + mloc] = __builtin_bit_cast(s16x4, pk);
            }
            __syncthreads();
            #pragma unroll
            for (int rep = 0; rep < 2; ++rep) {
                const int col = tid >> 3;
                const int seg = (tid & 7) + rep * 8;
                const int nn = n0 + (col >> 4) * 64 + jj * 16 + (col & 15);
                const int h = (nn & 1023) >> 6, d = nn & 63;
                const int mo = seg * 8;
                s16x8 v = *(const s16x8*)&ct[col * 136 + mo];
                *(s16x8*)&vto[((size_t)((bb * 16 + h) * 64 + d)) * 2048 + s0 + mo] = v;
            }
            __syncthreads();
        }
    }
}

// ---------------- flash attention (causal, static-max, swapped QK^T) ----------------
// r11 structure (double-buffered K/V staging) + T5 s_setprio around MFMA clusters.
__global__ __launch_bounds__(256, 2) void attn_fwd(
    const u16* __restrict__ q, const u16* __restrict__ k,
    const u16* __restrict__ vt, u16* __restrict__ ao)
{
    __shared__ u16 kt[2][8 * 512];
    __shared__ u16 vtl[2][8 * 512];
    __shared__ u16 plds[4 * 32 * 72];
    const int w = threadIdx.x >> 6, l = threadIdx.x & 63;
    const int lr = l & 15, lc = l >> 4;
    const int bh = blockIdx.x;
    const int cp = blockIdx.y;
    const u16* qp = q + (size_t)bh * 2048 * 64;
    const u16* kp = k + (size_t)bh * 2048 * 64;
    const u16* vp = vt + (size_t)bh * 64 * 2048;
    u16* pl = &plds[w * 2304];
    const int bb = bh >> 4, h = bh & 15;

    for (int pass = 0; pass < 2; ++pass) {
        const int C = pass ? (15 - cp) : cp;
        const int q0 = C * 128 + w * 32;
        const int nb = 2 * C + 2;
        const int diag = 2 * C + (w >> 1);

        s16x8 aQ[2][2];
        #pragma unroll
        for (int i = 0; i < 2; ++i)
            #pragma unroll
            for (int kk = 0; kk < 2; ++kk)
                aQ[i][kk] = *(const s16x8*)&qp[(q0 + i * 16 + lr) * 64 + kk * 32 + lc * 8];

        f32x4 O[2][4] = {};
        f32x4 lsv[2] = {};

        auto stage = [&](int t, int buf) {
            const int c0 = t * 64;
            if (w < 2) {
                #pragma unroll
                for (int gi = 0; gi < 4; ++gi) {
                    const int g = w * 4 + gi;
                    const int j = g >> 1, kk = g & 1;
                    gload16(kp + (c0 + j * 16 + lr) * 64 + kk * 32 + lc * 8,
                            &kt[buf][g * 512]);
                }
            } else {
                #pragma unroll
                for (int gi = 0; gi < 4; ++gi) {
                    const int g = (w - 2) * 4 + gi;
                    const int jd = g >> 1, kk = g & 1;
                    gload16(vp + (jd * 16 + lr) * 2048 + c0 + kk * 32 + lc * 8,
                            &vtl[buf][g * 512]);
                }
            }
        };

        __syncthreads();
        stage(0, 0);
        int cur = 0;

        for (int t = 0; t < nb; ++t) {
            __syncthreads();
            if (t + 1 < nb) stage(t + 1, cur ^ 1);

            if (t <= diag) {
                const int c0 = t * 64;
                f32x4 s[2][4] = {};
                __builtin_amdgcn_s_setprio(1);
                #pragma unroll
                for (int j = 0; j < 4; ++j) {
                    s16x8 k0 = *(const s16x8*)&kt[cur][(j * 2 + 0) * 512 + l * 8];
                    s16x8 k1 = *(const s16x8*)&kt[cur][(j * 2 + 1) * 512 + l * 8];
                    s[0][j] = mfma16(k0, aQ[0][0], s[0][j]);
                    s[0][j] = mfma16(k1, aQ[0][1], s[0][j]);
                    s[1][j] = mfma16(k0, aQ[1][0], s[1][j]);
                    s[1][j] = mfma16(k1, aQ[1][1], s[1][j]);
                }
                __builtin_amdgcn_s_setprio(0);
                if (t == diag) {
                    #pragma unroll
                    for (int i = 0; i < 2; ++i) {
                        const int qrow = q0 + i * 16 + lr;
                        #pragma unroll
                        for (int j = 0; j < 4; ++j) {
                            const int kvb = c0 + j * 16 + lc * 4;
                            #pragma unroll
                            for (int r = 0; r < 4; ++r)
                                if (kvb + r > qrow) s[i][j][r] = -1e30f;
                        }
                    }
                }
                #pragma unroll
                for (int i = 0; i < 2; ++i) {
                    #pragma unroll
                    for (int j = 0; j < 4; ++j)
                        #pragma unroll
                        for (int r = 0; r < 4; ++r)
                            s[i][j][r] = fexp2(s[i][j][r]);
                    lsv[i] += (s[i][0] + s[i][1]) + (s[i][2] + s[i][3]);
                    #pragma unroll
                    for (int j = 0; j < 4; ++j) {
                        uint2 pk;
                        pk.x = cvt_pk_bf16(s[i][j][0], s[i][j][1]);
                        pk.y = cvt_pk_bf16(s[i][j][2], s[i][j][3]);
                        *(s16x4*)&pl[(i * 16 + lr) * 72 + j * 16 + lc * 4] =
                            __builtin_bit_cast(s16x4, pk);
                    }
                }
                s16x8 aP[2][2];
                #pragma unroll
                for (int i = 0; i < 2; ++i)
                    #pragma unroll
                    for (int kk = 0; kk < 2; ++kk)
                        aP[i][kk] = *(const s16x8*)&pl[(i * 16 + lr) * 72 + kk * 32 + lc * 8];
                __builtin_amdgcn_s_setprio(1);
                #pragma unroll
                for (int jd = 0; jd < 4; ++jd) {
                    s16x8 v0 = *(const s16x8*)&vtl[cur][(jd * 2 + 0) * 512 + l * 8];
                    s16x8 v1 = *(const s16x8*)&vtl[cur][(jd * 2 + 1) * 512 + l * 8];
                    O[0][jd] = mfma16(aP[0][0], v0, O[0][jd]);
                    O[0][jd] = mfma16(aP[0][1], v1, O[0][jd]);
                    O[1][jd] = mfma16(aP[1][0], v0, O[1][jd]);
                    O[1][jd] = mfma16(aP[1][1], v1, O[1][jd]);
                }
                __builtin_amdgcn_s_setprio(0);
            }
            cur ^= 1;
        }

        float lsr[2];
        #pragma unroll
        for (int i = 0; i < 2; ++i) {
            float t2 = (lsv[i][0] + lsv[i][1]) + (lsv[i][2] + lsv[i][3]);
            t2 += __shfl_xor(t2, 16);
            t2 += __shfl_xor(t2, 32);
            lsr[i] = 1.0f / t2;
        }
        float inv[2][4];
        #pragma unroll
        for (int i = 0; i < 2; ++i)
            #pragma unroll
            for (int r = 0; r < 4; ++r)
                inv[i][r] = __shfl(lsr[i], lc * 4 + r);

        #pragma unroll
        for (int i = 0; i < 2; ++i)
            #pragma unroll
            for (int jd = 0; jd < 4; ++jd)
                #pragma unroll
                for (int r = 0; r < 4; ++r) {
                    const int srow = q0 + i * 16 + lc * 4 + r;
                    ao[((size_t)(bb * 2048 + srow)) * 1024 + h * 64 + jd * 16 + lr] =
                        f2bf(O[i][jd][r] * inv[i][r]);
                }
    }
}

// ---------------- output projection GEMM (r3 known-good structure) ----------------
__global__ __launch_bounds__(256) void gemm_out(
    const u16* __restrict__ A, const u16* __restrict__ B,
    const float* __restrict__ bias, float* __restrict__ out)
{
    __shared__ u16 As[128 * 32];
    __shared__ u16 Bs[128 * 32];
    const int tid = threadIdx.x;
    const int w = tid >> 6, l = tid & 63;
    const int lr = l & 15, lc = l >> 4;
    const int m0 = blockIdx.x * 128, n0 = blockIdx.y * 128;
    const int wm = (w >> 1) * 64, wn = (w & 1) * 64;

    const int srow = w * 32 + (l >> 2);
    const int scol = (l & 3) * 8;
    const u16* gA = A + (size_t)(m0 + srow) * K_DIM + scol;
    const u16* gB = B + (size_t)(n0 + srow) * K_DIM + scol;
    u16* lA = &As[w * 1024];
    u16* lB = &Bs[w * 1024];

    f32x4 acc[4][4] = {};

    for (int k0 = 0; k0 < K_DIM; k0 += 32) {
        __syncthreads();
        gload16(gA + k0, lA);
        gload16(gA + 16 * K_DIM + k0, lA + 512);
        gload16(gB + k0, lB);
        gload16(gB + 16 * K_DIM + k0, lB + 512);
        __syncthreads();
        s16x8 a[4], b[4];
        #pragma unroll
        for (int i = 0; i < 4; ++i)
            a[i] = *(const s16x8*)&As[(wm + i * 16 + lr) * 32 + lc * 8];
        #pragma unroll
        for (int j = 0; j < 4; ++j)
            b[j] = *(const s16x8*)&Bs[(wn + j * 16 + lr) * 32 + lc * 8];
        #pragma unroll
        for (int i = 0; i < 4; ++i)
            #pragma unroll
            for (int j = 0; j < 4; ++j)
                acc[i][j] = mfma16(a[i], b[j], acc[i][j]);
    }

    #pragma unroll
    for (int j = 0; j < 4; ++j) {
        const int n = n0 + wn + j * 16 + lr;
        const float bv = bias[n];
        #pragma unroll
        for (int i = 0; i < 4; ++i) {
            #pragma unroll
            for (int r = 0; r < 4; ++r) {
                const int m = m0 + wm + i * 16 + lc * 4 + r;
                out[(size_t)m * 1024 + n] = acc[i][j][r] + bv;
            }
        }
    }
}

// ---------------- launcher ----------------
extern "C" void kernel_launch(void* const* d_in, const int* in_sizes, int n_in,
                              void* d_out, int out_size, void* d_ws, size_t ws_size,
                              hipStream_t stream) {
    const float* x     = (const float*)d_in[0];
    const float* w_qkv = (const float*)d_in[1];
    const float* b_qkv = (const float*)d_in[2];
    const float* w_out = (const float*)d_in[3];
    const float* b_out = (const float*)d_in[4];
    float* out = (float*)d_out;

    char* ws = (char*)d_ws;
    u16* xb   = (u16*)(ws);                    // 8192x1024 bf16  (16 MB)
    u16* wqb  = (u16*)(ws + 16777216);         // 3072x1024 bf16  (6 MB)
    u16* wob  = (u16*)(ws + 23068672);         // 1024x1024 bf16  (2 MB)
    u16* qws  = (u16*)(ws + 25165824);         // [64][2048][64]  (16 MB)
    u16* kws  = (u16*)(ws + 41943040);         // [64][2048][64]  (16 MB)
    u16* vtws = (u16*)(ws + 58720256);         // [64][64][2048]  (16 MB)
    u16* attn = (u16*)(ws + 75497472);         // 8192x1024 bf16  (16 MB)

    cvt_f2bf<<<dim3(2048), 256, 0, stream>>>(x,     xb,  8388608 / 4);
    cvt_f2bf<<<dim3(2048), 256, 0, stream>>>(w_qkv, wqb, 3145728 / 4);
    cvt_f2bf<<<dim3(1024), 256, 0, stream>>>(w_out, wob, 1048576 / 4);

    gemm_qkv<<<dim3(64, 24), 256, 0, stream>>>(xb, wqb, b_qkv, qws, kws, vtws);
    attn_fwd<<<dim3(64, 8), 256, 0, stream>>>(qws, kws, vtws, attn);
    gemm_out<<<dim3(64, 8), 256, 0, stream>>>(attn, wob, b_out, out);
}

// Round 13
// 155.811 us; speedup vs baseline: 2.2813x; 1.0290x over previous
//
#include <hip/hip_runtime.h>
#include <stdint.h>

typedef __bf16 bf16x8 __attribute__((ext_vector_type(8)));
typedef short s16x8 __attribute__((ext_vector_type(8)));
typedef short s16x4 __attribute__((ext_vector_type(4)));
typedef float f32x4 __attribute__((ext_vector_type(4)));
typedef unsigned short u16;

#define K_DIM 1024

static __device__ __forceinline__ u16 f2bf(float f) {
    uint32_t x = __float_as_uint(f);
    x += 0x7fffu + ((x >> 16) & 1u);
    return (u16)(x >> 16);
}

static __device__ __forceinline__ f32x4 mfma16(s16x8 a, s16x8 b, f32x4 c) {
    return __builtin_amdgcn_mfma_f32_16x16x32_bf16(
        __builtin_bit_cast(bf16x8, a), __builtin_bit_cast(bf16x8, b), c, 0, 0, 0);
}

static __device__ __forceinline__ void gload16(const u16* g, u16* l) {
    __builtin_amdgcn_global_load_lds(
        (const __attribute__((address_space(1))) void*)g,
        (__attribute__((address_space(3))) void*)l,
        16, 0, 0);
}

static __device__ __forceinline__ uint32_t cvt_pk_bf16(float lo, float hi) {
    uint32_t r;
    asm("v_cvt_pk_bf16_f32 %0, %1, %2" : "=v"(r) : "v"(lo), "v"(hi));
    return r;
}

static __device__ __forceinline__ float fexp2(float x) {
#if __has_builtin(__builtin_amdgcn_exp2f)
    return __builtin_amdgcn_exp2f(x);
#else
    return __expf(x * 0.69314718056f);
#endif
}

// ---------------- fp32 -> bf16 conversion ----------------
__global__ void cvt_f2bf(const float* __restrict__ in, u16* __restrict__ out, int n4) {
    int stride = gridDim.x * blockDim.x;
    for (int i = blockIdx.x * blockDim.x + threadIdx.x; i < n4; i += stride) {
        float4 f = ((const float4*)in)[i];
        ushort4 o;
        o.x = f2bf(f.x); o.y = f2bf(f.y); o.z = f2bf(f.z); o.w = f2bf(f.w);
        ((ushort4*)out)[i] = o;
    }
}

// ---------------- QKV projection GEMM ----------------
// r10 XCD swizzle + LDS-transposed V epilogue + STAGE-AHEAD DOUBLE BUFFER
// (one barrier per K-step; next K-step's global_load_lds issued before the
// MFMAs of the current step -> staging latency hides under compute).
__global__ __launch_bounds__(256) void gemm_qkv(
    const u16* __restrict__ A, const u16* __restrict__ B,
    const float* __restrict__ bias,
    u16* __restrict__ qo, u16* __restrict__ ko, u16* __restrict__ vto)
{
    __shared__ u16 smem[16384];   // buf0: As[0..4095] Bs[4096..8191]; buf1 at +8192
    u16* ct = smem;               // V-epilogue transpose tile [32][136] aliases buf0
    const int tid = threadIdx.x;
    const int w = tid >> 6, l = tid & 63;
    const int lr = l & 15, lc = l >> 4;

    // XCD-aware bijective swizzle (nwg=1536): XCD c gets n-panels {3c,3c+1,3c+2}
    // (0.75MB B resident in its L2) x all m (A streams).
    const int flat = blockIdx.y * 64 + blockIdx.x;
    const int swz = (flat & 7) * 192 + (flat >> 3);
    const int m0 = (swz & 63) * 128, n0 = (swz >> 6) * 128;
    const int wm = (w >> 1) * 64, wn = (w & 1) * 64;

    const int srow = w * 32 + (l >> 2);
    const int scol = (l & 3) * 8;
    const u16* gA = A + (size_t)(m0 + srow) * K_DIM + scol;
    const u16* gB = B + (size_t)(n0 + srow) * K_DIM + scol;

    f32x4 acc[4][4] = {};

    auto stage = [&](int k0, int buf) {
        u16* lA = smem + buf * 8192 + w * 1024;
        u16* lB = smem + buf * 8192 + 4096 + w * 1024;
        gload16(gA + k0, lA);
        gload16(gA + 16 * K_DIM + k0, lA + 512);
        gload16(gB + k0, lB);
        gload16(gB + 16 * K_DIM + k0, lB + 512);
    };

    stage(0, 0);
    int cur = 0;

    for (int k0 = 0; k0 < K_DIM; k0 += 32) {
        __syncthreads();                       // buf[cur] staged (own vmcnt drained at barrier)
        if (k0 + 32 < K_DIM) stage(k0 + 32, cur ^ 1);
        const u16* As = smem + cur * 8192;
        const u16* Bs = As + 4096;
        s16x8 a[4], b[4];
        #pragma unroll
        for (int i = 0; i < 4; ++i)
            a[i] = *(const s16x8*)&As[(wm + i * 16 + lr) * 32 + lc * 8];
        #pragma unroll
        for (int j = 0; j < 4; ++j)
            b[j] = *(const s16x8*)&Bs[(wn + j * 16 + lr) * 32 + lc * 8];
        #pragma unroll
        for (int i = 0; i < 4; ++i)
            #pragma unroll
            for (int j = 0; j < 4; ++j)
                acc[i][j] = mfma16(a[i], b[j], acc[i][j]);
        cur ^= 1;
    }

    const int sec = n0 >> 10;   // block-uniform
    const int bb = m0 >> 11, s0 = m0 & 2047;

    if (sec < 2) {
        #pragma unroll
        for (int j = 0; j < 4; ++j) {
            const int n = n0 + wn + j * 16 + lr;
            const float bv = bias[n];
            const int h = (n & 1023) >> 6, d = n & 63;
            #pragma unroll
            for (int i = 0; i < 4; ++i) {
                #pragma unroll
                for (int r = 0; r < 4; ++r) {
                    const int m = m0 + wm + i * 16 + lc * 4 + r;
                    const int s = m & 2047;
                    float v = acc[i][j][r] + bv;
                    if (sec == 0)
                        qo[((size_t)((bb * 16 + h) * 2048 + s)) * 64 + d] = f2bf(v * 0.18033688f);
                    else
                        ko[((size_t)((bb * 16 + h) * 2048 + s)) * 64 + d] = f2bf(v);
                }
            }
        }
    } else {
        __syncthreads();          // all LDS reads done before ct aliases buf0
        // V: transpose 16-col groups through LDS, store s-contiguous 16B runs
        #pragma unroll
        for (int jj = 0; jj < 4; ++jj) {
            const int nl = (wn >> 6) * 16 + lr;
            const float bv = bias[n0 + wn + jj * 16 + lr];
            #pragma unroll
            for (int i = 0; i < 4; ++i) {
                const int mloc = wm + i * 16 + lc * 4;
                uint2 pk;
                pk.x = cvt_pk_bf16(acc[i][jj][0] + bv, acc[i][jj][1] + bv);
                pk.y = cvt_pk_bf16(acc[i][jj][2] + bv, acc[i][jj][3] + bv);
                *(s16x4*)&ct[nl * 136 + mloc] = __builtin_bit_cast(s16x4, pk);
            }
            __syncthreads();
            #pragma unroll
            for (int rep = 0; rep < 2; ++rep) {
                const int col = tid >> 3;
                const int seg = (tid & 7) + rep * 8;
                const int nn = n0 + (col >> 4) * 64 + jj * 16 + (col & 15);
                const int h = (nn & 1023) >> 6, d = nn & 63;
                const int mo = seg * 8;
                s16x8 v = *(const s16x8*)&ct[col * 136 + mo];
                *(s16x8*)&vto[((size_t)((bb * 16 + h) * 64 + d)) * 2048 + s0 + mo] = v;
            }
            __syncthreads();
        }
    }
}

// ---------------- flash attention (causal, static-max, swapped QK^T) ----------------
// r12 known-good: 4-wave blocks, K/V LDS-shared fragment-major, double-buffered
// staging, setprio around MFMA clusters.
__global__ __launch_bounds__(256, 2) void attn_fwd(
    const u16* __restrict__ q, const u16* __restrict__ k,
    const u16* __restrict__ vt, u16* __restrict__ ao)
{
    __shared__ u16 kt[2][8 * 512];
    __shared__ u16 vtl[2][8 * 512];
    __shared__ u16 plds[4 * 32 * 72];
    const int w = threadIdx.x >> 6, l = threadIdx.x & 63;
    const int lr = l & 15, lc = l >> 4;
    const int bh = blockIdx.x;
    const int cp = blockIdx.y;
    const u16* qp = q + (size_t)bh * 2048 * 64;
    const u16* kp = k + (size_t)bh * 2048 * 64;
    const u16* vp = vt + (size_t)bh * 64 * 2048;
    u16* pl = &plds[w * 2304];
    const int bb = bh >> 4, h = bh & 15;

    for (int pass = 0; pass < 2; ++pass) {
        const int C = pass ? (15 - cp) : cp;
        const int q0 = C * 128 + w * 32;
        const int nb = 2 * C + 2;
        const int diag = 2 * C + (w >> 1);

        s16x8 aQ[2][2];
        #pragma unroll
        for (int i = 0; i < 2; ++i)
            #pragma unroll
            for (int kk = 0; kk < 2; ++kk)
                aQ[i][kk] = *(const s16x8*)&qp[(q0 + i * 16 + lr) * 64 + kk * 32 + lc * 8];

        f32x4 O[2][4] = {};
        f32x4 lsv[2] = {};

        auto stage = [&](int t, int buf) {
            const int c0 = t * 64;
            if (w < 2) {
                #pragma unroll
                for (int gi = 0; gi < 4; ++gi) {
                    const int g = w * 4 + gi;
                    const int j = g >> 1, kk = g & 1;
                    gload16(kp + (c0 + j * 16 + lr) * 64 + kk * 32 + lc * 8,
                            &kt[buf][g * 512]);
                }
            } else {
                #pragma unroll
                for (int gi = 0; gi < 4; ++gi) {
                    const int g = (w - 2) * 4 + gi;
                    const int jd = g >> 1, kk = g & 1;
                    gload16(vp + (jd * 16 + lr) * 2048 + c0 + kk * 32 + lc * 8,
                            &vtl[buf][g * 512]);
                }
            }
        };

        __syncthreads();
        stage(0, 0);
        int cur = 0;

        for (int t = 0; t < nb; ++t) {
            __syncthreads();
            if (t + 1 < nb) stage(t + 1, cur ^ 1);

            if (t <= diag) {
                const int c0 = t * 64;
                f32x4 s[2][4] = {};
                __builtin_amdgcn_s_setprio(1);
                #pragma unroll
                for (int j = 0; j < 4; ++j) {
                    s16x8 k0 = *(const s16x8*)&kt[cur][(j * 2 + 0) * 512 + l * 8];
                    s16x8 k1 = *(const s16x8*)&kt[cur][(j * 2 + 1) * 512 + l * 8];
                    s[0][j] = mfma16(k0, aQ[0][0], s[0][j]);
                    s[0][j] = mfma16(k1, aQ[0][1], s[0][j]);
                    s[1][j] = mfma16(k0, aQ[1][0], s[1][j]);
                    s[1][j] = mfma16(k1, aQ[1][1], s[1][j]);
                }
                __builtin_amdgcn_s_setprio(0);
                if (t == diag) {
                    #pragma unroll
                    for (int i = 0; i < 2; ++i) {
                        const int qrow = q0 + i * 16 + lr;
                        #pragma unroll
                        for (int j = 0; j < 4; ++j) {
                            const int kvb = c0 + j * 16 + lc * 4;
                            #pragma unroll
                            for (int r = 0; r < 4; ++r)
                                if (kvb + r > qrow) s[i][j][r] = -1e30f;
                        }
                    }
                }
                #pragma unroll
                for (int i = 0; i < 2; ++i) {
                    #pragma unroll
                    for (int j = 0; j < 4; ++j)
                        #pragma unroll
                        for (int r = 0; r < 4; ++r)
                            s[i][j][r] = fexp2(s[i][j][r]);
                    lsv[i] += (s[i][0] + s[i][1]) + (s[i][2] + s[i][3]);
                    #pragma unroll
                    for (int j = 0; j < 4; ++j) {
                        uint2 pk;
                        pk.x = cvt_pk_bf16(s[i][j][0], s[i][j][1]);
                        pk.y = cvt_pk_bf16(s[i][j][2], s[i][j][3]);
                        *(s16x4*)&pl[(i * 16 + lr) * 72 + j * 16 + lc * 4] =
                            __builtin_bit_cast(s16x4, pk);
                    }
                }
                s16x8 aP[2][2];
                #pragma unroll
                for (int i = 0; i < 2; ++i)
                    #pragma unroll
                    for (int kk = 0; kk < 2; ++kk)
                        aP[i][kk] = *(const s16x8*)&pl[(i * 16 + lr) * 72 + kk * 32 + lc * 8];
                __builtin_amdgcn_s_setprio(1);
                #pragma unroll
                for (int jd = 0; jd < 4; ++jd) {
                    s16x8 v0 = *(const s16x8*)&vtl[cur][(jd * 2 + 0) * 512 + l * 8];
                    s16x8 v1 = *(const s16x8*)&vtl[cur][(jd * 2 + 1) * 512 + l * 8];
                    O[0][jd] = mfma16(aP[0][0], v0, O[0][jd]);
                    O[0][jd] = mfma16(aP[0][1], v1, O[0][jd]);
                    O[1][jd] = mfma16(aP[1][0], v0, O[1][jd]);
                    O[1][jd] = mfma16(aP[1][1], v1, O[1][jd]);
                }
                __builtin_amdgcn_s_setprio(0);
            }
            cur ^= 1;
        }

        float lsr[2];
        #pragma unroll
        for (int i = 0; i < 2; ++i) {
            float t2 = (lsv[i][0] + lsv[i][1]) + (lsv[i][2] + lsv[i][3]);
            t2 += __shfl_xor(t2, 16);
            t2 += __shfl_xor(t2, 32);
            lsr[i] = 1.0f / t2;
        }
        float inv[2][4];
        #pragma unroll
        for (int i = 0; i < 2; ++i)
            #pragma unroll
            for (int r = 0; r < 4; ++r)
                inv[i][r] = __shfl(lsr[i], lc * 4 + r);

        #pragma unroll
        for (int i = 0; i < 2; ++i)
            #pragma unroll
            for (int jd = 0; jd < 4; ++jd)
                #pragma unroll
                for (int r = 0; r < 4; ++r) {
                    const int srow = q0 + i * 16 + lc * 4 + r;
                    ao[((size_t)(bb * 2048 + srow)) * 1024 + h * 64 + jd * 16 + lr] =
                        f2bf(O[i][jd][r] * inv[i][r]);
                }
    }
}

// ---------------- output projection GEMM ----------------
// r3 structure + stage-ahead double buffer (same pattern as gemm_qkv).
__global__ __launch_bounds__(256) void gemm_out(
    const u16* __restrict__ A, const u16* __restrict__ B,
    const float* __restrict__ bias, float* __restrict__ out)
{
    __shared__ u16 smem[16384];
    const int tid = threadIdx.x;
    const int w = tid >> 6, l = tid & 63;
    const int lr = l & 15, lc = l >> 4;
    const int m0 = blockIdx.x * 128, n0 = blockIdx.y * 128;
    const int wm = (w >> 1) * 64, wn = (w & 1) * 64;

    const int srow = w * 32 + (l >> 2);
    const int scol = (l & 3) * 8;
    const u16* gA = A + (size_t)(m0 + srow) * K_DIM + scol;
    const u16* gB = B + (size_t)(n0 + srow) * K_DIM + scol;

    f32x4 acc[4][4] = {};

    auto stage = [&](int k0, int buf) {
        u16* lA = smem + buf * 8192 + w * 1024;
        u16* lB = smem + buf * 8192 + 4096 + w * 1024;
        gload16(gA + k0, lA);
        gload16(gA + 16 * K_DIM + k0, lA + 512);
        gload16(gB + k0, lB);
        gload16(gB + 16 * K_DIM + k0, lB + 512);
    };

    stage(0, 0);
    int cur = 0;

    for (int k0 = 0; k0 < K_DIM; k0 += 32) {
        __syncthreads();
        if (k0 + 32 < K_DIM) stage(k0 + 32, cur ^ 1);
        const u16* As = smem + cur * 8192;
        const u16* Bs = As + 4096;
        s16x8 a[4], b[4];
        #pragma unroll
        for (int i = 0; i < 4; ++i)
            a[i] = *(const s16x8*)&As[(wm + i * 16 + lr) * 32 + lc * 8];
        #pragma unroll
        for (int j = 0; j < 4; ++j)
            b[j] = *(const s16x8*)&Bs[(wn + j * 16 + lr) * 32 + lc * 8];
        #pragma unroll
        for (int i = 0; i < 4; ++i)
            #pragma unroll
            for (int j = 0; j < 4; ++j)
                acc[i][j] = mfma16(a[i], b[j], acc[i][j]);
        cur ^= 1;
    }

    #pragma unroll
    for (int j = 0; j < 4; ++j) {
        const int n = n0 + wn + j * 16 + lr;
        const float bv = bias[n];
        #pragma unroll
        for (int i = 0; i < 4; ++i) {
            #pragma unroll
            for (int r = 0; r < 4; ++r) {
                const int m = m0 + wm + i * 16 + lc * 4 + r;
                out[(size_t)m * 1024 + n] = acc[i][j][r] + bv;
            }
        }
    }
}

// ---------------- launcher ----------------
extern "C" void kernel_launch(void* const* d_in, const int* in_sizes, int n_in,
                              void* d_out, int out_size, void* d_ws, size_t ws_size,
                              hipStream_t stream) {
    const float* x     = (const float*)d_in[0];
    const float* w_qkv = (const float*)d_in[1];
    const float* b_qkv = (const float*)d_in[2];
    const float* w_out = (const float*)d_in[3];
    const float* b_out = (const float*)d_in[4];
    float* out = (float*)d_out;

    char* ws = (char*)d_ws;
    u16* xb   = (u16*)(ws);                    // 8192x1024 bf16  (16 MB)
    u16* wqb  = (u16*)(ws + 16777216);         // 3072x1024 bf16  (6 MB)
    u16* wob  = (u16*)(ws + 23068672);         // 1024x1024 bf16  (2 MB)
    u16* qws  = (u16*)(ws + 25165824);         // [64][2048][64]  (16 MB)
    u16* kws  = (u16*)(ws + 41943040);         // [64][2048][64]  (16 MB)
    u16* vtws = (u16*)(ws + 58720256);         // [64][64][2048]  (16 MB)
    u16* attn = (u16*)(ws + 75497472);         // 8192x1024 bf16  (16 MB)

    cvt_f2bf<<<dim3(2048), 256, 0, stream>>>(x,     xb,  8388608 / 4);
    cvt_f2bf<<<dim3(2048), 256, 0, stream>>>(w_qkv, wqb, 3145728 / 4);
    cvt_f2bf<<<dim3(1024), 256, 0, stream>>>(w_out, wob, 1048576 / 4);

    gemm_qkv<<<dim3(64, 24), 256, 0, stream>>>(xb, wqb, b_qkv, qws, kws, vtws);
    attn_fwd<<<dim3(64, 8), 256, 0, stream>>>(qws, kws, vtws, attn);
    gemm_out<<<dim3(64, 8), 256, 0, stream>>>(attn, wob, b_out, out);
}

// Round 14
// 154.244 us; speedup vs baseline: 2.3045x; 1.0102x over previous
//
#include <hip/hip_runtime.h>
#include <stdint.h>

typedef __bf16 bf16x8 __attribute__((ext_vector_type(8)));
typedef short s16x8 __attribute__((ext_vector_type(8)));
typedef short s16x4 __attribute__((ext_vector_type(4)));
typedef float f32x4 __attribute__((ext_vector_type(4)));
typedef unsigned short u16;

#define K_DIM 1024

static __device__ __forceinline__ u16 f2bf(float f) {
    uint32_t x = __float_as_uint(f);
    x += 0x7fffu + ((x >> 16) & 1u);
    return (u16)(x >> 16);
}

static __device__ __forceinline__ f32x4 mfma16(s16x8 a, s16x8 b, f32x4 c) {
    return __builtin_amdgcn_mfma_f32_16x16x32_bf16(
        __builtin_bit_cast(bf16x8, a), __builtin_bit_cast(bf16x8, b), c, 0, 0, 0);
}

static __device__ __forceinline__ void gload16(const u16* g, u16* l) {
    __builtin_amdgcn_global_load_lds(
        (const __attribute__((address_space(1))) void*)g,
        (__attribute__((address_space(3))) void*)l,
        16, 0, 0);
}

static __device__ __forceinline__ uint32_t cvt_pk_bf16(float lo, float hi) {
    uint32_t r;
    asm("v_cvt_pk_bf16_f32 %0, %1, %2" : "=v"(r) : "v"(lo), "v"(hi));
    return r;
}

static __device__ __forceinline__ float fexp2(float x) {
#if __has_builtin(__builtin_amdgcn_exp2f)
    return __builtin_amdgcn_exp2f(x);
#else
    return __expf(x * 0.69314718056f);
#endif
}

// ---------------- fp32 -> bf16 conversion ----------------
__global__ void cvt_f2bf(const float* __restrict__ in, u16* __restrict__ out, int n4) {
    int stride = gridDim.x * blockDim.x;
    for (int i = blockIdx.x * blockDim.x + threadIdx.x; i < n4; i += stride) {
        float4 f = ((const float4*)in)[i];
        ushort4 o;
        o.x = f2bf(f.x); o.y = f2bf(f.y); o.z = f2bf(f.z); o.w = f2bf(f.w);
        ((ushort4*)out)[i] = o;
    }
}

// ---------------- QKV projection GEMM ----------------
// BK=64 (r6-verified XOR-swizzled layout) + stage-ahead double buffer (r13
// pattern): 16 barriers instead of 32, compute phase ~2x -> drain stall covered.
// XCD swizzle (r10/r12-proven) + LDS-transposed V epilogue.
__global__ __launch_bounds__(256) void gemm_qkv(
    const u16* __restrict__ A, const u16* __restrict__ B,
    const float* __restrict__ bias,
    u16* __restrict__ qo, u16* __restrict__ ko, u16* __restrict__ vto)
{
    __shared__ u16 smem[32768];   // buf0: A[0..8191] B[8192..16383]; buf1 at +16384
    u16* ct = smem;               // V-epilogue transpose tile [32][136] aliases buf0
    const int tid = threadIdx.x;
    const int w = tid >> 6, l = tid & 63;
    const int lr = l & 15, lc = l >> 4;

    // XCD-aware bijective swizzle (nwg=1536): XCD c gets n-panels {3c..3c+2}
    // (0.75MB B L2-resident) x all m (A streams).
    const int flat = blockIdx.y * 64 + blockIdx.x;
    const int swz = (flat & 7) * 192 + (flat >> 3);
    const int m0 = (swz & 63) * 128, n0 = (swz >> 6) * 128;
    const int wm = (w >> 1) * 64, wn = (w & 1) * 64;

    // staging (r6 layout): wave w, instr g -> rows g*32 + w*8 .. +8
    // lane l: row += l>>3, src col16 = ((l&7) ^ (l>>3)) * 8  [XOR pre-swizzle]
    const int srow = w * 8 + (l >> 3);
    const int scol = ((l & 7) ^ (l >> 3)) * 8;
    const u16* gA = A + (size_t)(m0 + srow) * K_DIM + scol;
    const u16* gB = B + (size_t)(n0 + srow) * K_DIM + scol;

    f32x4 acc[4][4] = {};

    auto stage = [&](int k0, int buf) {
        u16* base = smem + buf * 16384;
        #pragma unroll
        for (int g = 0; g < 4; ++g) {
            gload16(gA + (size_t)g * 32 * K_DIM + k0, base + (g * 32 + w * 8) * 64);
            gload16(gB + (size_t)g * 32 * K_DIM + k0, base + 8192 + (g * 32 + w * 8) * 64);
        }
    };

    stage(0, 0);
    int cur = 0;

    for (int k0 = 0; k0 < K_DIM; k0 += 64) {
        __syncthreads();                       // buf[cur] staged
        if (k0 + 64 < K_DIM) stage(k0 + 64, cur ^ 1);
        const u16* As = smem + cur * 16384;
        const u16* Bs = As + 8192;
        #pragma unroll
        for (int kk = 0; kk < 2; ++kk) {
            s16x8 a[4], b[4];
            #pragma unroll
            for (int i = 0; i < 4; ++i) {
                const int row = wm + i * 16 + lr;
                a[i] = *(const s16x8*)&As[row * 64 + ((kk * 32 + lc * 8) ^ ((row & 7) * 8))];
            }
            #pragma unroll
            for (int j = 0; j < 4; ++j) {
                const int row = wn + j * 16 + lr;
                b[j] = *(const s16x8*)&Bs[row * 64 + ((kk * 32 + lc * 8) ^ ((row & 7) * 8))];
            }
            #pragma unroll
            for (int i = 0; i < 4; ++i)
                #pragma unroll
                for (int j = 0; j < 4; ++j)
                    acc[i][j] = mfma16(a[i], b[j], acc[i][j]);
        }
        cur ^= 1;
    }

    const int sec = n0 >> 10;   // block-uniform
    const int bb = m0 >> 11, s0 = m0 & 2047;

    if (sec < 2) {
        #pragma unroll
        for (int j = 0; j < 4; ++j) {
            const int n = n0 + wn + j * 16 + lr;
            const float bv = bias[n];
            const int h = (n & 1023) >> 6, d = n & 63;
            #pragma unroll
            for (int i = 0; i < 4; ++i) {
                #pragma unroll
                for (int r = 0; r < 4; ++r) {
                    const int m = m0 + wm + i * 16 + lc * 4 + r;
                    const int s = m & 2047;
                    float v = acc[i][j][r] + bv;
                    if (sec == 0)
                        qo[((size_t)((bb * 16 + h) * 2048 + s)) * 64 + d] = f2bf(v * 0.18033688f);
                    else
                        ko[((size_t)((bb * 16 + h) * 2048 + s)) * 64 + d] = f2bf(v);
                }
            }
        }
    } else {
        __syncthreads();          // all LDS reads done before ct aliases buf0
        // V: transpose 16-col groups through LDS, store s-contiguous 16B runs
        #pragma unroll
        for (int jj = 0; jj < 4; ++jj) {
            const int nl = (wn >> 6) * 16 + lr;
            const float bv = bias[n0 + wn + jj * 16 + lr];
            #pragma unroll
            for (int i = 0; i < 4; ++i) {
                const int mloc = wm + i * 16 + lc * 4;
                uint2 pk;
                pk.x = cvt_pk_bf16(acc[i][jj][0] + bv, acc[i][jj][1] + bv);
                pk.y = cvt_pk_bf16(acc[i][jj][2] + bv, acc[i][jj][3] + bv);
                *(s16x4*)&ct[nl * 136 + mloc] = __builtin_bit_cast(s16x4, pk);
            }
            __syncthreads();
            #pragma unroll
            for (int rep = 0; rep < 2; ++rep) {
                const int col = tid >> 3;
                const int seg = (tid & 7) + rep * 8;
                const int nn = n0 + (col >> 4) * 64 + jj * 16 + (col & 15);
                const int h = (nn & 1023) >> 6, d = nn & 63;
                const int mo = seg * 8;
                s16x8 v = *(const s16x8*)&ct[col * 136 + mo];
                *(s16x8*)&vto[((size_t)((bb * 16 + h) * 64 + d)) * 2048 + s0 + mo] = v;
            }
            __syncthreads();
        }
    }
}

// ---------------- flash attention (causal, static-max, swapped QK^T) ----------------
// r12/r13 known-good: 4-wave blocks, K/V LDS-shared fragment-major, double-
// buffered staging, setprio around MFMA clusters.
__global__ __launch_bounds__(256, 2) void attn_fwd(
    const u16* __restrict__ q, const u16* __restrict__ k,
    const u16* __restrict__ vt, u16* __restrict__ ao)
{
    __shared__ u16 kt[2][8 * 512];
    __shared__ u16 vtl[2][8 * 512];
    __shared__ u16 plds[4 * 32 * 72];
    const int w = threadIdx.x >> 6, l = threadIdx.x & 63;
    const int lr = l & 15, lc = l >> 4;
    const int bh = blockIdx.x;
    const int cp = blockIdx.y;
    const u16* qp = q + (size_t)bh * 2048 * 64;
    const u16* kp = k + (size_t)bh * 2048 * 64;
    const u16* vp = vt + (size_t)bh * 64 * 2048;
    u16* pl = &plds[w * 2304];
    const int bb = bh >> 4, h = bh & 15;

    for (int pass = 0; pass < 2; ++pass) {
        const int C = pass ? (15 - cp) : cp;
        const int q0 = C * 128 + w * 32;
        const int nb = 2 * C + 2;
        const int diag = 2 * C + (w >> 1);

        s16x8 aQ[2][2];
        #pragma unroll
        for (int i = 0; i < 2; ++i)
            #pragma unroll
            for (int kk = 0; kk < 2; ++kk)
                aQ[i][kk] = *(const s16x8*)&qp[(q0 + i * 16 + lr) * 64 + kk * 32 + lc * 8];

        f32x4 O[2][4] = {};
        f32x4 lsv[2] = {};

        auto stage = [&](int t, int buf) {
            const int c0 = t * 64;
            if (w < 2) {
                #pragma unroll
                for (int gi = 0; gi < 4; ++gi) {
                    const int g = w * 4 + gi;
                    const int j = g >> 1, kk = g & 1;
                    gload16(kp + (c0 + j * 16 + lr) * 64 + kk * 32 + lc * 8,
                            &kt[buf][g * 512]);
                }
            } else {
                #pragma unroll
                for (int gi = 0; gi < 4; ++gi) {
                    const int g = (w - 2) * 4 + gi;
                    const int jd = g >> 1, kk = g & 1;
                    gload16(vp + (jd * 16 + lr) * 2048 + c0 + kk * 32 + lc * 8,
                            &vtl[buf][g * 512]);
                }
            }
        };

        __syncthreads();
        stage(0, 0);
        int cur = 0;

        for (int t = 0; t < nb; ++t) {
            __syncthreads();
            if (t + 1 < nb) stage(t + 1, cur ^ 1);

            if (t <= diag) {
                const int c0 = t * 64;
                f32x4 s[2][4] = {};
                __builtin_amdgcn_s_setprio(1);
                #pragma unroll
                for (int j = 0; j < 4; ++j) {
                    s16x8 k0 = *(const s16x8*)&kt[cur][(j * 2 + 0) * 512 + l * 8];
                    s16x8 k1 = *(const s16x8*)&kt[cur][(j * 2 + 1) * 512 + l * 8];
                    s[0][j] = mfma16(k0, aQ[0][0], s[0][j]);
                    s[0][j] = mfma16(k1, aQ[0][1], s[0][j]);
                    s[1][j] = mfma16(k0, aQ[1][0], s[1][j]);
                    s[1][j] = mfma16(k1, aQ[1][1], s[1][j]);
                }
                __builtin_amdgcn_s_setprio(0);
                if (t == diag) {
                    #pragma unroll
                    for (int i = 0; i < 2; ++i) {
                        const int qrow = q0 + i * 16 + lr;
                        #pragma unroll
                        for (int j = 0; j < 4; ++j) {
                            const int kvb = c0 + j * 16 + lc * 4;
                            #pragma unroll
                            for (int r = 0; r < 4; ++r)
                                if (kvb + r > qrow) s[i][j][r] = -1e30f;
                        }
                    }
                }
                #pragma unroll
                for (int i = 0; i < 2; ++i) {
                    #pragma unroll
                    for (int j = 0; j < 4; ++j)
                        #pragma unroll
                        for (int r = 0; r < 4; ++r)
                            s[i][j][r] = fexp2(s[i][j][r]);
                    lsv[i] += (s[i][0] + s[i][1]) + (s[i][2] + s[i][3]);
                    #pragma unroll
                    for (int j = 0; j < 4; ++j) {
                        uint2 pk;
                        pk.x = cvt_pk_bf16(s[i][j][0], s[i][j][1]);
                        pk.y = cvt_pk_bf16(s[i][j][2], s[i][j][3]);
                        *(s16x4*)&pl[(i * 16 + lr) * 72 + j * 16 + lc * 4] =
                            __builtin_bit_cast(s16x4, pk);
                    }
                }
                s16x8 aP[2][2];
                #pragma unroll
                for (int i = 0; i < 2; ++i)
                    #pragma unroll
                    for (int kk = 0; kk < 2; ++kk)
                        aP[i][kk] = *(const s16x8*)&pl[(i * 16 + lr) * 72 + kk * 32 + lc * 8];
                __builtin_amdgcn_s_setprio(1);
                #pragma unroll
                for (int jd = 0; jd < 4; ++jd) {
                    s16x8 v0 = *(const s16x8*)&vtl[cur][(jd * 2 + 0) * 512 + l * 8];
                    s16x8 v1 = *(const s16x8*)&vtl[cur][(jd * 2 + 1) * 512 + l * 8];
                    O[0][jd] = mfma16(aP[0][0], v0, O[0][jd]);
                    O[0][jd] = mfma16(aP[0][1], v1, O[0][jd]);
                    O[1][jd] = mfma16(aP[1][0], v0, O[1][jd]);
                    O[1][jd] = mfma16(aP[1][1], v1, O[1][jd]);
                }
                __builtin_amdgcn_s_setprio(0);
            }
            cur ^= 1;
        }

        float lsr[2];
        #pragma unroll
        for (int i = 0; i < 2; ++i) {
            float t2 = (lsv[i][0] + lsv[i][1]) + (lsv[i][2] + lsv[i][3]);
            t2 += __shfl_xor(t2, 16);
            t2 += __shfl_xor(t2, 32);
            lsr[i] = 1.0f / t2;
        }
        float inv[2][4];
        #pragma unroll
        for (int i = 0; i < 2; ++i)
            #pragma unroll
            for (int r = 0; r < 4; ++r)
                inv[i][r] = __shfl(lsr[i], lc * 4 + r);

        #pragma unroll
        for (int i = 0; i < 2; ++i)
            #pragma unroll
            for (int jd = 0; jd < 4; ++jd)
                #pragma unroll
                for (int r = 0; r < 4; ++r) {
                    const int srow = q0 + i * 16 + lc * 4 + r;
                    ao[((size_t)(bb * 2048 + srow)) * 1024 + h * 64 + jd * 16 + lr] =
                        f2bf(O[i][jd][r] * inv[i][r]);
                }
    }
}

// ---------------- output projection GEMM ----------------
// BK=64 swizzled + stage-ahead double buffer (same as gemm_qkv), natural mapping.
__global__ __launch_bounds__(256) void gemm_out(
    const u16* __restrict__ A, const u16* __restrict__ B,
    const float* __restrict__ bias, float* __restrict__ out)
{
    __shared__ u16 smem[32768];
    const int tid = threadIdx.x;
    const int w = tid >> 6, l = tid & 63;
    const int lr = l & 15, lc = l >> 4;
    const int m0 = blockIdx.x * 128, n0 = blockIdx.y * 128;
    const int wm = (w >> 1) * 64, wn = (w & 1) * 64;

    const int srow = w * 8 + (l >> 3);
    const int scol = ((l & 7) ^ (l >> 3)) * 8;
    const u16* gA = A + (size_t)(m0 + srow) * K_DIM + scol;
    const u16* gB = B + (size_t)(n0 + srow) * K_DIM + scol;

    f32x4 acc[4][4] = {};

    auto stage = [&](int k0, int buf) {
        u16* base = smem + buf * 16384;
        #pragma unroll
        for (int g = 0; g < 4; ++g) {
            gload16(gA + (size_t)g * 32 * K_DIM + k0, base + (g * 32 + w * 8) * 64);
            gload16(gB + (size_t)g * 32 * K_DIM + k0, base + 8192 + (g * 32 + w * 8) * 64);
        }
    };

    stage(0, 0);
    int cur = 0;

    for (int k0 = 0; k0 < K_DIM; k0 += 64) {
        __syncthreads();
        if (k0 + 64 < K_DIM) stage(k0 + 64, cur ^ 1);
        const u16* As = smem + cur * 16384;
        const u16* Bs = As + 8192;
        #pragma unroll
        for (int kk = 0; kk < 2; ++kk) {
            s16x8 a[4], b[4];
            #pragma unroll
            for (int i = 0; i < 4; ++i) {
                const int row = wm + i * 16 + lr;
                a[i] = *(const s16x8*)&As[row * 64 + ((kk * 32 + lc * 8) ^ ((row & 7) * 8))];
            }
            #pragma unroll
            for (int j = 0; j < 4; ++j) {
                const int row = wn + j * 16 + lr;
                b[j] = *(const s16x8*)&Bs[row * 64 + ((kk * 32 + lc * 8) ^ ((row & 7) * 8))];
            }
            #pragma unroll
            for (int i = 0; i < 4; ++i)
                #pragma unroll
                for (int j = 0; j < 4; ++j)
                    acc[i][j] = mfma16(a[i], b[j], acc[i][j]);
        }
        cur ^= 1;
    }

    #pragma unroll
    for (int j = 0; j < 4; ++j) {
        const int n = n0 + wn + j * 16 + lr;
        const float bv = bias[n];
        #pragma unroll
        for (int i = 0; i < 4; ++i) {
            #pragma unroll
            for (int r = 0; r < 4; ++r) {
                const int m = m0 + wm + i * 16 + lc * 4 + r;
                out[(size_t)m * 1024 + n] = acc[i][j][r] + bv;
            }
        }
    }
}

// ---------------- launcher ----------------
extern "C" void kernel_launch(void* const* d_in, const int* in_sizes, int n_in,
                              void* d_out, int out_size, void* d_ws, size_t ws_size,
                              hipStream_t stream) {
    const float* x     = (const float*)d_in[0];
    const float* w_qkv = (const float*)d_in[1];
    const float* b_qkv = (const float*)d_in[2];
    const float* w_out = (const float*)d_in[3];
    const float* b_out = (const float*)d_in[4];
    float* out = (float*)d_out;

    char* ws = (char*)d_ws;
    u16* xb   = (u16*)(ws);                    // 8192x1024 bf16  (16 MB)
    u16* wqb  = (u16*)(ws + 16777216);         // 3072x1024 bf16  (6 MB)
    u16* wob  = (u16*)(ws + 23068672);         // 1024x1024 bf16  (2 MB)
    u16* qws  = (u16*)(ws + 25165824);         // [64][2048][64]  (16 MB)
    u16* kws  = (u16*)(ws + 41943040);         // [64][2048][64]  (16 MB)
    u16* vtws = (u16*)(ws + 58720256);         // [64][64][2048]  (16 MB)
    u16* attn = (u16*)(ws + 75497472);         // 8192x1024 bf16  (16 MB)

    cvt_f2bf<<<dim3(2048), 256, 0, stream>>>(x,     xb,  8388608 / 4);
    cvt_f2bf<<<dim3(2048), 256, 0, stream>>>(w_qkv, wqb, 3145728 / 4);
    cvt_f2bf<<<dim3(1024), 256, 0, stream>>>(w_out, wob, 1048576 / 4);

    gemm_qkv<<<dim3(64, 24), 256, 0, stream>>>(xb, wqb, b_qkv, qws, kws, vtws);
    attn_fwd<<<dim3(64, 8), 256, 0, stream>>>(qws, kws, vtws, attn);
    gemm_out<<<dim3(64, 8), 256, 0, stream>>>(attn, wob, b_out, out);
}

// Round 15
// 135.735 us; speedup vs baseline: 2.6188x; 1.1364x over previous
//
#include <hip/hip_runtime.h>
#include <stdint.h>

typedef __bf16 bf16x8 __attribute__((ext_vector_type(8)));
typedef short s16x8 __attribute__((ext_vector_type(8)));
typedef short s16x4 __attribute__((ext_vector_type(4)));
typedef float f32x4 __attribute__((ext_vector_type(4)));
typedef unsigned short u16;

#define K_DIM 1024

static __device__ __forceinline__ u16 f2bf(float f) {
    uint32_t x = __float_as_uint(f);
    x += 0x7fffu + ((x >> 16) & 1u);
    return (u16)(x >> 16);
}

static __device__ __forceinline__ f32x4 mfma16(s16x8 a, s16x8 b, f32x4 c) {
    return __builtin_amdgcn_mfma_f32_16x16x32_bf16(
        __builtin_bit_cast(bf16x8, a), __builtin_bit_cast(bf16x8, b), c, 0, 0, 0);
}

static __device__ __forceinline__ void gload16(const u16* g, u16* l) {
    __builtin_amdgcn_global_load_lds(
        (const __attribute__((address_space(1))) void*)g,
        (__attribute__((address_space(3))) void*)l,
        16, 0, 0);
}

static __device__ __forceinline__ uint32_t cvt_pk_bf16(float lo, float hi) {
    uint32_t r;
    asm("v_cvt_pk_bf16_f32 %0, %1, %2" : "=v"(r) : "v"(lo), "v"(hi));
    return r;
}

static __device__ __forceinline__ float fexp2(float x) {
#if __has_builtin(__builtin_amdgcn_exp2f)
    return __builtin_amdgcn_exp2f(x);
#else
    return __expf(x * 0.69314718056f);
#endif
}

// ---------------- fp32 -> bf16 conversion ----------------
__global__ void cvt_f2bf(const float* __restrict__ in, u16* __restrict__ out, int n4) {
    int stride = gridDim.x * blockDim.x;
    for (int i = blockIdx.x * blockDim.x + threadIdx.x; i < n4; i += stride) {
        float4 f = ((const float4*)in)[i];
        ushort4 o;
        o.x = f2bf(f.x); o.y = f2bf(f.y); o.z = f2bf(f.z); o.w = f2bf(f.w);
        ((ushort4*)out)[i] = o;
    }
}

// ---------------- QKV projection GEMM ----------------
// BK=64 XOR-swizzled + stage-ahead double buffer + 2D SUPERTILE XCD MAPPING:
// XCD c owns m-panels {8c..8c+7} (A-chunk 2MB L2-RESIDENT all kernel) and
// walks n-panels one at a time (B-panel 256KB hot). Chip A-traffic = 16MB
// (once), B = 48MB  ->  ~66MB total vs 200MB with the n-partition swizzle.
__global__ __launch_bounds__(256) void gemm_qkv(
    const u16* __restrict__ A, const u16* __restrict__ B,
    const float* __restrict__ bias,
    u16* __restrict__ qo, u16* __restrict__ ko, u16* __restrict__ vto)
{
    __shared__ u16 smem[32768];   // buf0: A[0..8191] B[8192..16383]; buf1 at +16384
    u16* ct = smem;               // V-epilogue transpose tile [32][136] aliases buf0
    const int tid = threadIdx.x;
    const int w = tid >> 6, l = tid & 63;
    const int lr = l & 15, lc = l >> 4;

    // 2D supertile XCD mapping (bijective over 64x24):
    // f&7 = XCD; m-panel = c*8 + (j&7), n-panel = j>>3.
    const int f = blockIdx.y * 64 + blockIdx.x;
    const int c = f & 7, j = f >> 3;
    const int m0 = (c * 8 + (j & 7)) * 128;
    const int n0 = (j >> 3) * 128;
    const int wm = (w >> 1) * 64, wn = (w & 1) * 64;

    // staging (r6 layout): wave w, instr g -> rows g*32 + w*8 .. +8
    // lane l: row += l>>3, src col16 = ((l&7) ^ (l>>3)) * 8  [XOR pre-swizzle]
    const int srow = w * 8 + (l >> 3);
    const int scol = ((l & 7) ^ (l >> 3)) * 8;
    const u16* gA = A + (size_t)(m0 + srow) * K_DIM + scol;
    const u16* gB = B + (size_t)(n0 + srow) * K_DIM + scol;

    f32x4 acc[4][4] = {};

    auto stage = [&](int k0, int buf) {
        u16* base = smem + buf * 16384;
        #pragma unroll
        for (int g = 0; g < 4; ++g) {
            gload16(gA + (size_t)g * 32 * K_DIM + k0, base + (g * 32 + w * 8) * 64);
            gload16(gB + (size_t)g * 32 * K_DIM + k0, base + 8192 + (g * 32 + w * 8) * 64);
        }
    };

    stage(0, 0);
    int cur = 0;

    for (int k0 = 0; k0 < K_DIM; k0 += 64) {
        __syncthreads();                       // buf[cur] staged
        if (k0 + 64 < K_DIM) stage(k0 + 64, cur ^ 1);
        const u16* As = smem + cur * 16384;
        const u16* Bs = As + 8192;
        #pragma unroll
        for (int kk = 0; kk < 2; ++kk) {
            s16x8 a[4], b[4];
            #pragma unroll
            for (int i = 0; i < 4; ++i) {
                const int row = wm + i * 16 + lr;
                a[i] = *(const s16x8*)&As[row * 64 + ((kk * 32 + lc * 8) ^ ((row & 7) * 8))];
            }
            #pragma unroll
            for (int jn = 0; jn < 4; ++jn) {
                const int row = wn + jn * 16 + lr;
                b[jn] = *(const s16x8*)&Bs[row * 64 + ((kk * 32 + lc * 8) ^ ((row & 7) * 8))];
            }
            #pragma unroll
            for (int i = 0; i < 4; ++i)
                #pragma unroll
                for (int jn = 0; jn < 4; ++jn)
                    acc[i][jn] = mfma16(a[i], b[jn], acc[i][jn]);
        }
        cur ^= 1;
    }

    const int sec = n0 >> 10;   // block-uniform
    const int bb = m0 >> 11, s0 = m0 & 2047;

    if (sec < 2) {
        #pragma unroll
        for (int jn = 0; jn < 4; ++jn) {
            const int n = n0 + wn + jn * 16 + lr;
            const float bv = bias[n];
            const int h = (n & 1023) >> 6, d = n & 63;
            #pragma unroll
            for (int i = 0; i < 4; ++i) {
                #pragma unroll
                for (int r = 0; r < 4; ++r) {
                    const int m = m0 + wm + i * 16 + lc * 4 + r;
                    const int s = m & 2047;
                    float v = acc[i][jn][r] + bv;
                    if (sec == 0)
                        qo[((size_t)((bb * 16 + h) * 2048 + s)) * 64 + d] = f2bf(v * 0.18033688f);
                    else
                        ko[((size_t)((bb * 16 + h) * 2048 + s)) * 64 + d] = f2bf(v);
                }
            }
        }
    } else {
        __syncthreads();          // all LDS reads done before ct aliases buf0
        // V: transpose 16-col groups through LDS, store s-contiguous 16B runs
        #pragma unroll
        for (int jj = 0; jj < 4; ++jj) {
            const int nl = (wn >> 6) * 16 + lr;
            const float bv = bias[n0 + wn + jj * 16 + lr];
            #pragma unroll
            for (int i = 0; i < 4; ++i) {
                const int mloc = wm + i * 16 + lc * 4;
                uint2 pk;
                pk.x = cvt_pk_bf16(acc[i][jj][0] + bv, acc[i][jj][1] + bv);
                pk.y = cvt_pk_bf16(acc[i][jj][2] + bv, acc[i][jj][3] + bv);
                *(s16x4*)&ct[nl * 136 + mloc] = __builtin_bit_cast(s16x4, pk);
            }
            __syncthreads();
            #pragma unroll
            for (int rep = 0; rep < 2; ++rep) {
                const int col = tid >> 3;
                const int seg = (tid & 7) + rep * 8;
                const int nn = n0 + (col >> 4) * 64 + jj * 16 + (col & 15);
                const int h = (nn & 1023) >> 6, d = nn & 63;
                const int mo = seg * 8;
                s16x8 v = *(const s16x8*)&ct[col * 136 + mo];
                *(s16x8*)&vto[((size_t)((bb * 16 + h) * 64 + d)) * 2048 + s0 + mo] = v;
            }
            __syncthreads();
        }
    }
}

// ---------------- flash attention (causal, static-max, swapped QK^T) ----------------
// r12/r13 known-good: 4-wave blocks, K/V LDS-shared fragment-major, double-
// buffered staging, setprio around MFMA clusters.
__global__ __launch_bounds__(256, 2) void attn_fwd(
    const u16* __restrict__ q, const u16* __restrict__ k,
    const u16* __restrict__ vt, u16* __restrict__ ao)
{
    __shared__ u16 kt[2][8 * 512];
    __shared__ u16 vtl[2][8 * 512];
    __shared__ u16 plds[4 * 32 * 72];
    const int w = threadIdx.x >> 6, l = threadIdx.x & 63;
    const int lr = l & 15, lc = l >> 4;
    const int bh = blockIdx.x;
    const int cp = blockIdx.y;
    const u16* qp = q + (size_t)bh * 2048 * 64;
    const u16* kp = k + (size_t)bh * 2048 * 64;
    const u16* vp = vt + (size_t)bh * 64 * 2048;
    u16* pl = &plds[w * 2304];
    const int bb = bh >> 4, h = bh & 15;

    for (int pass = 0; pass < 2; ++pass) {
        const int C = pass ? (15 - cp) : cp;
        const int q0 = C * 128 + w * 32;
        const int nb = 2 * C + 2;
        const int diag = 2 * C + (w >> 1);

        s16x8 aQ[2][2];
        #pragma unroll
        for (int i = 0; i < 2; ++i)
            #pragma unroll
            for (int kk = 0; kk < 2; ++kk)
                aQ[i][kk] = *(const s16x8*)&qp[(q0 + i * 16 + lr) * 64 + kk * 32 + lc * 8];

        f32x4 O[2][4] = {};
        f32x4 lsv[2] = {};

        auto stage = [&](int t, int buf) {
            const int c0 = t * 64;
            if (w < 2) {
                #pragma unroll
                for (int gi = 0; gi < 4; ++gi) {
                    const int g = w * 4 + gi;
                    const int jx = g >> 1, kk = g & 1;
                    gload16(kp + (c0 + jx * 16 + lr) * 64 + kk * 32 + lc * 8,
                            &kt[buf][g * 512]);
                }
            } else {
                #pragma unroll
                for (int gi = 0; gi < 4; ++gi) {
                    const int g = (w - 2) * 4 + gi;
                    const int jd = g >> 1, kk = g & 1;
                    gload16(vp + (jd * 16 + lr) * 2048 + c0 + kk * 32 + lc * 8,
                            &vtl[buf][g * 512]);
                }
            }
        };

        __syncthreads();
        stage(0, 0);
        int cur = 0;

        for (int t = 0; t < nb; ++t) {
            __syncthreads();
            if (t + 1 < nb) stage(t + 1, cur ^ 1);

            if (t <= diag) {
                const int c0 = t * 64;
                f32x4 s[2][4] = {};
                __builtin_amdgcn_s_setprio(1);
                #pragma unroll
                for (int jx = 0; jx < 4; ++jx) {
                    s16x8 k0 = *(const s16x8*)&kt[cur][(jx * 2 + 0) * 512 + l * 8];
                    s16x8 k1 = *(const s16x8*)&kt[cur][(jx * 2 + 1) * 512 + l * 8];
                    s[0][jx] = mfma16(k0, aQ[0][0], s[0][jx]);
                    s[0][jx] = mfma16(k1, aQ[0][1], s[0][jx]);
                    s[1][jx] = mfma16(k0, aQ[1][0], s[1][jx]);
                    s[1][jx] = mfma16(k1, aQ[1][1], s[1][jx]);
                }
                __builtin_amdgcn_s_setprio(0);
                if (t == diag) {
                    #pragma unroll
                    for (int i = 0; i < 2; ++i) {
                        const int qrow = q0 + i * 16 + lr;
                        #pragma unroll
                        for (int jx = 0; jx < 4; ++jx) {
                            const int kvb = c0 + jx * 16 + lc * 4;
                            #pragma unroll
                            for (int r = 0; r < 4; ++r)
                                if (kvb + r > qrow) s[i][jx][r] = -1e30f;
                        }
                    }
                }
                #pragma unroll
                for (int i = 0; i < 2; ++i) {
                    #pragma unroll
                    for (int jx = 0; jx < 4; ++jx)
                        #pragma unroll
                        for (int r = 0; r < 4; ++r)
                            s[i][jx][r] = fexp2(s[i][jx][r]);
                    lsv[i] += (s[i][0] + s[i][1]) + (s[i][2] + s[i][3]);
                    #pragma unroll
                    for (int jx = 0; jx < 4; ++jx) {
                        uint2 pk;
                        pk.x = cvt_pk_bf16(s[i][jx][0], s[i][jx][1]);
                        pk.y = cvt_pk_bf16(s[i][jx][2], s[i][jx][3]);
                        *(s16x4*)&pl[(i * 16 + lr) * 72 + jx * 16 + lc * 4] =
                            __builtin_bit_cast(s16x4, pk);
                    }
                }
                s16x8 aP[2][2];
                #pragma unroll
                for (int i = 0; i < 2; ++i)
                    #pragma unroll
                    for (int kk = 0; kk < 2; ++kk)
                        aP[i][kk] = *(const s16x8*)&pl[(i * 16 + lr) * 72 + kk * 32 + lc * 8];
                __builtin_amdgcn_s_setprio(1);
                #pragma unroll
                for (int jd = 0; jd < 4; ++jd) {
                    s16x8 v0 = *(const s16x8*)&vtl[cur][(jd * 2 + 0) * 512 + l * 8];
                    s16x8 v1 = *(const s16x8*)&vtl[cur][(jd * 2 + 1) * 512 + l * 8];
                    O[0][jd] = mfma16(aP[0][0], v0, O[0][jd]);
                    O[0][jd] = mfma16(aP[0][1], v1, O[0][jd]);
                    O[1][jd] = mfma16(aP[1][0], v0, O[1][jd]);
                    O[1][jd] = mfma16(aP[1][1], v1, O[1][jd]);
                }
                __builtin_amdgcn_s_setprio(0);
            }
            cur ^= 1;
        }

        float lsr[2];
        #pragma unroll
        for (int i = 0; i < 2; ++i) {
            float t2 = (lsv[i][0] + lsv[i][1]) + (lsv[i][2] + lsv[i][3]);
            t2 += __shfl_xor(t2, 16);
            t2 += __shfl_xor(t2, 32);
            lsr[i] = 1.0f / t2;
        }
        float inv[2][4];
        #pragma unroll
        for (int i = 0; i < 2; ++i)
            #pragma unroll
            for (int r = 0; r < 4; ++r)
                inv[i][r] = __shfl(lsr[i], lc * 4 + r);

        #pragma unroll
        for (int i = 0; i < 2; ++i)
            #pragma unroll
            for (int jd = 0; jd < 4; ++jd)
                #pragma unroll
                for (int r = 0; r < 4; ++r) {
                    const int srow = q0 + i * 16 + lc * 4 + r;
                    ao[((size_t)(bb * 2048 + srow)) * 1024 + h * 64 + jd * 16 + lr] =
                        f2bf(O[i][jd][r] * inv[i][r]);
                }
    }
}

// ---------------- output projection GEMM ----------------
// BK=64 swizzled + stage-ahead dbuf + 2D supertile XCD mapping (m-partition).
__global__ __launch_bounds__(256) void gemm_out(
    const u16* __restrict__ A, const u16* __restrict__ B,
    const float* __restrict__ bias, float* __restrict__ out)
{
    __shared__ u16 smem[32768];
    const int tid = threadIdx.x;
    const int w = tid >> 6, l = tid & 63;
    const int lr = l & 15, lc = l >> 4;

    // 2D supertile XCD mapping (bijective over 64x8)
    const int f = blockIdx.y * 64 + blockIdx.x;
    const int c = f & 7, j = f >> 3;          // j in [0,64)
    const int m0 = (c * 8 + (j & 7)) * 128;
    const int n0 = (j >> 3) * 128;            // [0,8)
    const int wm = (w >> 1) * 64, wn = (w & 1) * 64;

    const int srow = w * 8 + (l >> 3);
    const int scol = ((l & 7) ^ (l >> 3)) * 8;
    const u16* gA = A + (size_t)(m0 + srow) * K_DIM + scol;
    const u16* gB = B + (size_t)(n0 + srow) * K_DIM + scol;

    f32x4 acc[4][4] = {};

    auto stage = [&](int k0, int buf) {
        u16* base = smem + buf * 16384;
        #pragma unroll
        for (int g = 0; g < 4; ++g) {
            gload16(gA + (size_t)g * 32 * K_DIM + k0, base + (g * 32 + w * 8) * 64);
            gload16(gB + (size_t)g * 32 * K_DIM + k0, base + 8192 + (g * 32 + w * 8) * 64);
        }
    };

    stage(0, 0);
    int cur = 0;

    for (int k0 = 0; k0 < K_DIM; k0 += 64) {
        __syncthreads();
        if (k0 + 64 < K_DIM) stage(k0 + 64, cur ^ 1);
        const u16* As = smem + cur * 16384;
        const u16* Bs = As + 8192;
        #pragma unroll
        for (int kk = 0; kk < 2; ++kk) {
            s16x8 a[4], b[4];
            #pragma unroll
            for (int i = 0; i < 4; ++i) {
                const int row = wm + i * 16 + lr;
                a[i] = *(const s16x8*)&As[row * 64 + ((kk * 32 + lc * 8) ^ ((row & 7) * 8))];
            }
            #pragma unroll
            for (int jn = 0; jn < 4; ++jn) {
                const int row = wn + jn * 16 + lr;
                b[jn] = *(const s16x8*)&Bs[row * 64 + ((kk * 32 + lc * 8) ^ ((row & 7) * 8))];
            }
            #pragma unroll
            for (int i = 0; i < 4; ++i)
                #pragma unroll
                for (int jn = 0; jn < 4; ++jn)
                    acc[i][jn] = mfma16(a[i], b[jn], acc[i][jn]);
        }
        cur ^= 1;
    }

    #pragma unroll
    for (int jn = 0; jn < 4; ++jn) {
        const int n = n0 + wn + jn * 16 + lr;
        const float bv = bias[n];
        #pragma unroll
        for (int i = 0; i < 4; ++i) {
            #pragma unroll
            for (int r = 0; r < 4; ++r) {
                const int m = m0 + wm + i * 16 + lc * 4 + r;
                out[(size_t)m * 1024 + n] = acc[i][jn][r] + bv;
            }
        }
    }
}

// ---------------- launcher ----------------
extern "C" void kernel_launch(void* const* d_in, const int* in_sizes, int n_in,
                              void* d_out, int out_size, void* d_ws, size_t ws_size,
                              hipStream_t stream) {
    const float* x     = (const float*)d_in[0];
    const float* w_qkv = (const float*)d_in[1];
    const float* b_qkv = (const float*)d_in[2];
    const float* w_out = (const float*)d_in[3];
    const float* b_out = (const float*)d_in[4];
    float* out = (float*)d_out;

    char* ws = (char*)d_ws;
    u16* xb   = (u16*)(ws);                    // 8192x1024 bf16  (16 MB)
    u16* wqb  = (u16*)(ws + 16777216);         // 3072x1024 bf16  (6 MB)
    u16* wob  = (u16*)(ws + 23068672);         // 1024x1024 bf16  (2 MB)
    u16* qws  = (u16*)(ws + 25165824);         // [64][2048][64]  (16 MB)
    u16* kws  = (u16*)(ws + 41943040);         // [64][2048][64]  (16 MB)
    u16* vtws = (u16*)(ws + 58720256);         // [64][64][2048]  (16 MB)
    u16* attn = (u16*)(ws + 75497472);         // 8192x1024 bf16  (16 MB)

    cvt_f2bf<<<dim3(2048), 256, 0, stream>>>(x,     xb,  8388608 / 4);
    cvt_f2bf<<<dim3(2048), 256, 0, stream>>>(w_qkv, wqb, 3145728 / 4);
    cvt_f2bf<<<dim3(1024), 256, 0, stream>>>(w_out, wob, 1048576 / 4);

    gemm_qkv<<<dim3(64, 24), 256, 0, stream>>>(xb, wqb, b_qkv, qws, kws, vtws);
    attn_fwd<<<dim3(64, 8), 256, 0, stream>>>(qws, kws, vtws, attn);
    gemm_out<<<dim3(64, 8), 256, 0, stream>>>(attn, wob, b_out, out);
}

// Round 16
// 135.132 us; speedup vs baseline: 2.6304x; 1.0045x over previous
//
#include <hip/hip_runtime.h>
#include <stdint.h>

typedef __bf16 bf16x8 __attribute__((ext_vector_type(8)));
typedef short s16x8 __attribute__((ext_vector_type(8)));
typedef short s16x4 __attribute__((ext_vector_type(4)));
typedef float f32x4 __attribute__((ext_vector_type(4)));
typedef unsigned short u16;

#define K_DIM 1024

static __device__ __forceinline__ u16 f2bf(float f) {
    uint32_t x = __float_as_uint(f);
    x += 0x7fffu + ((x >> 16) & 1u);
    return (u16)(x >> 16);
}

static __device__ __forceinline__ f32x4 mfma16(s16x8 a, s16x8 b, f32x4 c) {
    return __builtin_amdgcn_mfma_f32_16x16x32_bf16(
        __builtin_bit_cast(bf16x8, a), __builtin_bit_cast(bf16x8, b), c, 0, 0, 0);
}

static __device__ __forceinline__ void gload16(const u16* g, u16* l) {
    __builtin_amdgcn_global_load_lds(
        (const __attribute__((address_space(1))) void*)g,
        (__attribute__((address_space(3))) void*)l,
        16, 0, 0);
}

static __device__ __forceinline__ uint32_t cvt_pk_bf16(float lo, float hi) {
    uint32_t r;
    asm("v_cvt_pk_bf16_f32 %0, %1, %2" : "=v"(r) : "v"(lo), "v"(hi));
    return r;
}

static __device__ __forceinline__ float fexp2(float x) {
#if __has_builtin(__builtin_amdgcn_exp2f)
    return __builtin_amdgcn_exp2f(x);
#else
    return __expf(x * 0.69314718056f);
#endif
}

// ---------------- fused fp32 -> bf16 conversion (one launch) ----------------
__global__ void cvt_all(const float* __restrict__ x, const float* __restrict__ wq,
                        const float* __restrict__ wo,
                        u16* __restrict__ xb, u16* __restrict__ wqb,
                        u16* __restrict__ wob) {
    const int stride = gridDim.x * blockDim.x;
    const int tid = blockIdx.x * blockDim.x + threadIdx.x;
    for (int i = tid; i < 2097152; i += stride) {          // x: 8M floats / 4
        float4 f = ((const float4*)x)[i];
        ushort4 o;
        o.x = f2bf(f.x); o.y = f2bf(f.y); o.z = f2bf(f.z); o.w = f2bf(f.w);
        ((ushort4*)xb)[i] = o;
    }
    for (int i = tid; i < 786432; i += stride) {           // w_qkv: 3M floats / 4
        float4 f = ((const float4*)wq)[i];
        ushort4 o;
        o.x = f2bf(f.x); o.y = f2bf(f.y); o.z = f2bf(f.z); o.w = f2bf(f.w);
        ((ushort4*)wqb)[i] = o;
    }
    for (int i = tid; i < 262144; i += stride) {           // w_out: 1M floats / 4
        float4 f = ((const float4*)wo)[i];
        ushort4 o;
        o.x = f2bf(f.x); o.y = f2bf(f.y); o.z = f2bf(f.z); o.w = f2bf(f.w);
        ((ushort4*)wob)[i] = o;
    }
}

// ---------------- QKV projection GEMM (r15 known-good) ----------------
// BK=64 XOR-swizzled + stage-ahead dbuf + 2D supertile XCD mapping (XCD owns
// 8 m-panels, A-chunk L2-resident; walks n). LDS-transposed V epilogue.
__global__ __launch_bounds__(256) void gemm_qkv(
    const u16* __restrict__ A, const u16* __restrict__ B,
    const float* __restrict__ bias,
    u16* __restrict__ qo, u16* __restrict__ ko, u16* __restrict__ vto)
{
    __shared__ u16 smem[32768];   // buf0: A[0..8191] B[8192..16383]; buf1 at +16384
    u16* ct = smem;               // V-epilogue transpose tile [32][136] aliases buf0
    const int tid = threadIdx.x;
    const int w = tid >> 6, l = tid & 63;
    const int lr = l & 15, lc = l >> 4;

    const int f = blockIdx.y * 64 + blockIdx.x;
    const int c = f & 7, j = f >> 3;
    const int m0 = (c * 8 + (j & 7)) * 128;
    const int n0 = (j >> 3) * 128;
    const int wm = (w >> 1) * 64, wn = (w & 1) * 64;

    const int srow = w * 8 + (l >> 3);
    const int scol = ((l & 7) ^ (l >> 3)) * 8;
    const u16* gA = A + (size_t)(m0 + srow) * K_DIM + scol;
    const u16* gB = B + (size_t)(n0 + srow) * K_DIM + scol;

    f32x4 acc[4][4] = {};

    auto stage = [&](int k0, int buf) {
        u16* base = smem + buf * 16384;
        #pragma unroll
        for (int g = 0; g < 4; ++g) {
            gload16(gA + (size_t)g * 32 * K_DIM + k0, base + (g * 32 + w * 8) * 64);
            gload16(gB + (size_t)g * 32 * K_DIM + k0, base + 8192 + (g * 32 + w * 8) * 64);
        }
    };

    stage(0, 0);
    int cur = 0;

    for (int k0 = 0; k0 < K_DIM; k0 += 64) {
        __syncthreads();
        if (k0 + 64 < K_DIM) stage(k0 + 64, cur ^ 1);
        const u16* As = smem + cur * 16384;
        const u16* Bs = As + 8192;
        #pragma unroll
        for (int kk = 0; kk < 2; ++kk) {
            s16x8 a[4], b[4];
            #pragma unroll
            for (int i = 0; i < 4; ++i) {
                const int row = wm + i * 16 + lr;
                a[i] = *(const s16x8*)&As[row * 64 + ((kk * 32 + lc * 8) ^ ((row & 7) * 8))];
            }
            #pragma unroll
            for (int jn = 0; jn < 4; ++jn) {
                const int row = wn + jn * 16 + lr;
                b[jn] = *(const s16x8*)&Bs[row * 64 + ((kk * 32 + lc * 8) ^ ((row & 7) * 8))];
            }
            #pragma unroll
            for (int i = 0; i < 4; ++i)
                #pragma unroll
                for (int jn = 0; jn < 4; ++jn)
                    acc[i][jn] = mfma16(a[i], b[jn], acc[i][jn]);
        }
        cur ^= 1;
    }

    const int sec = n0 >> 10;
    const int bb = m0 >> 11, s0 = m0 & 2047;

    if (sec < 2) {
        #pragma unroll
        for (int jn = 0; jn < 4; ++jn) {
            const int n = n0 + wn + jn * 16 + lr;
            const float bv = bias[n];
            const int h = (n & 1023) >> 6, d = n & 63;
            #pragma unroll
            for (int i = 0; i < 4; ++i) {
                #pragma unroll
                for (int r = 0; r < 4; ++r) {
                    const int m = m0 + wm + i * 16 + lc * 4 + r;
                    const int s = m & 2047;
                    float v = acc[i][jn][r] + bv;
                    if (sec == 0)
                        qo[((size_t)((bb * 16 + h) * 2048 + s)) * 64 + d] = f2bf(v * 0.18033688f);
                    else
                        ko[((size_t)((bb * 16 + h) * 2048 + s)) * 64 + d] = f2bf(v);
                }
            }
        }
    } else {
        __syncthreads();
        #pragma unroll
        for (int jj = 0; jj < 4; ++jj) {
            const int nl = (wn >> 6) * 16 + lr;
            const float bv = bias[n0 + wn + jj * 16 + lr];
            #pragma unroll
            for (int i = 0; i < 4; ++i) {
                const int mloc = wm + i * 16 + lc * 4;
                uint2 pk;
                pk.x = cvt_pk_bf16(acc[i][jj][0] + bv, acc[i][jj][1] + bv);
                pk.y = cvt_pk_bf16(acc[i][jj][2] + bv, acc[i][jj][3] + bv);
                *(s16x4*)&ct[nl * 136 + mloc] = __builtin_bit_cast(s16x4, pk);
            }
            __syncthreads();
            #pragma unroll
            for (int rep = 0; rep < 2; ++rep) {
                const int col = tid >> 3;
                const int seg = (tid & 7) + rep * 8;
                const int nn = n0 + (col >> 4) * 64 + jj * 16 + (col & 15);
                const int h = (nn & 1023) >> 6, d = nn & 63;
                const int mo = seg * 8;
                s16x8 v = *(const s16x8*)&ct[col * 136 + mo];
                *(s16x8*)&vto[((size_t)((bb * 16 + h) * 64 + d)) * 2048 + s0 + mo] = v;
            }
            __syncthreads();
        }
    }
}

// ---------------- flash attention (causal, static-max, swapped QK^T) ----------------
// One block = one 128-row chunk C (no pairing): grid (64,16) = 1024 blocks,
// dispatched LONGEST-FIRST (C = 15 - blockIdx.y) for backfill balance;
// launch_bounds(256,3) + 50.4KB LDS -> 3 blocks/CU = 3 waves/SIMD.
// V fragments hoisted before softmax (latency hides under exp2 VALU).
__global__ __launch_bounds__(256, 3) void attn_fwd(
    const u16* __restrict__ q, const u16* __restrict__ k,
    const u16* __restrict__ vt, u16* __restrict__ ao)
{
    __shared__ u16 kt[2][8 * 512];
    __shared__ u16 vtl[2][8 * 512];
    __shared__ u16 plds[4 * 32 * 72];
    const int w = threadIdx.x >> 6, l = threadIdx.x & 63;
    const int lr = l & 15, lc = l >> 4;
    const int bh = blockIdx.x;
    const int C = 15 - blockIdx.y;            // longest blocks dispatch first
    const u16* qp = q + (size_t)bh * 2048 * 64;
    const u16* kp = k + (size_t)bh * 2048 * 64;
    const u16* vp = vt + (size_t)bh * 64 * 2048;
    u16* pl = &plds[w * 2304];
    const int bb = bh >> 4, h = bh & 15;

    const int q0 = C * 128 + w * 32;
    const int nb = 2 * C + 2;
    const int diag = 2 * C + (w >> 1);

    s16x8 aQ[2][2];
    #pragma unroll
    for (int i = 0; i < 2; ++i)
        #pragma unroll
        for (int kk = 0; kk < 2; ++kk)
            aQ[i][kk] = *(const s16x8*)&qp[(q0 + i * 16 + lr) * 64 + kk * 32 + lc * 8];

    f32x4 O[2][4] = {};
    f32x4 lsv[2] = {};

    auto stage = [&](int t, int buf) {
        const int c0 = t * 64;
        if (w < 2) {
            #pragma unroll
            for (int gi = 0; gi < 4; ++gi) {
                const int g = w * 4 + gi;
                const int jx = g >> 1, kk = g & 1;
                gload16(kp + (c0 + jx * 16 + lr) * 64 + kk * 32 + lc * 8,
                        &kt[buf][g * 512]);
            }
        } else {
            #pragma unroll
            for (int gi = 0; gi < 4; ++gi) {
                const int g = (w - 2) * 4 + gi;
                const int jd = g >> 1, kk = g & 1;
                gload16(vp + (jd * 16 + lr) * 2048 + c0 + kk * 32 + lc * 8,
                        &vtl[buf][g * 512]);
            }
        }
    };

    stage(0, 0);
    int cur = 0;

    for (int t = 0; t < nb; ++t) {
        __syncthreads();
        if (t + 1 < nb) stage(t + 1, cur ^ 1);

        if (t <= diag) {
            const int c0 = t * 64;
            f32x4 s[2][4] = {};
            __builtin_amdgcn_s_setprio(1);
            #pragma unroll
            for (int jx = 0; jx < 4; ++jx) {
                s16x8 k0 = *(const s16x8*)&kt[cur][(jx * 2 + 0) * 512 + l * 8];
                s16x8 k1 = *(const s16x8*)&kt[cur][(jx * 2 + 1) * 512 + l * 8];
                s[0][jx] = mfma16(k0, aQ[0][0], s[0][jx]);
                s[0][jx] = mfma16(k1, aQ[0][1], s[0][jx]);
                s[1][jx] = mfma16(k0, aQ[1][0], s[1][jx]);
                s[1][jx] = mfma16(k1, aQ[1][1], s[1][jx]);
            }
            __builtin_amdgcn_s_setprio(0);
            // V-fragment hoist: LDS reads land while exp2 VALU runs
            s16x8 vf[4][2];
            #pragma unroll
            for (int jd = 0; jd < 4; ++jd)
                #pragma unroll
                for (int kk = 0; kk < 2; ++kk)
                    vf[jd][kk] = *(const s16x8*)&vtl[cur][(jd * 2 + kk) * 512 + l * 8];
            if (t == diag) {
                #pragma unroll
                for (int i = 0; i < 2; ++i) {
                    const int qrow = q0 + i * 16 + lr;
                    #pragma unroll
                    for (int jx = 0; jx < 4; ++jx) {
                        const int kvb = c0 + jx * 16 + lc * 4;
                        #pragma unroll
                        for (int r = 0; r < 4; ++r)
                            if (kvb + r > qrow) s[i][jx][r] = -1e30f;
                    }
                }
            }
            #pragma unroll
            for (int i = 0; i < 2; ++i) {
                #pragma unroll
                for (int jx = 0; jx < 4; ++jx)
                    #pragma unroll
                    for (int r = 0; r < 4; ++r)
                        s[i][jx][r] = fexp2(s[i][jx][r]);
                lsv[i] += (s[i][0] + s[i][1]) + (s[i][2] + s[i][3]);
                #pragma unroll
                for (int jx = 0; jx < 4; ++jx) {
                    uint2 pk;
                    pk.x = cvt_pk_bf16(s[i][jx][0], s[i][jx][1]);
                    pk.y = cvt_pk_bf16(s[i][jx][2], s[i][jx][3]);
                    *(s16x4*)&pl[(i * 16 + lr) * 72 + jx * 16 + lc * 4] =
                        __builtin_bit_cast(s16x4, pk);
                }
            }
            s16x8 aP[2][2];
            #pragma unroll
            for (int i = 0; i < 2; ++i)
                #pragma unroll
                for (int kk = 0; kk < 2; ++kk)
                    aP[i][kk] = *(const s16x8*)&pl[(i * 16 + lr) * 72 + kk * 32 + lc * 8];
            __builtin_amdgcn_s_setprio(1);
            #pragma unroll
            for (int jd = 0; jd < 4; ++jd) {
                O[0][jd] = mfma16(aP[0][0], vf[jd][0], O[0][jd]);
                O[0][jd] = mfma16(aP[0][1], vf[jd][1], O[0][jd]);
                O[1][jd] = mfma16(aP[1][0], vf[jd][0], O[1][jd]);
                O[1][jd] = mfma16(aP[1][1], vf[jd][1], O[1][jd]);
            }
            __builtin_amdgcn_s_setprio(0);
        }
        cur ^= 1;
    }

    float lsr[2];
    #pragma unroll
    for (int i = 0; i < 2; ++i) {
        float t2 = (lsv[i][0] + lsv[i][1]) + (lsv[i][2] + lsv[i][3]);
        t2 += __shfl_xor(t2, 16);
        t2 += __shfl_xor(t2, 32);
        lsr[i] = 1.0f / t2;
    }
    float inv[2][4];
    #pragma unroll
    for (int i = 0; i < 2; ++i)
        #pragma unroll
        for (int r = 0; r < 4; ++r)
            inv[i][r] = __shfl(lsr[i], lc * 4 + r);

    #pragma unroll
    for (int i = 0; i < 2; ++i)
        #pragma unroll
        for (int jd = 0; jd < 4; ++jd)
            #pragma unroll
            for (int r = 0; r < 4; ++r) {
                const int srow = q0 + i * 16 + lc * 4 + r;
                ao[((size_t)(bb * 2048 + srow)) * 1024 + h * 64 + jd * 16 + lr] =
                    f2bf(O[i][jd][r] * inv[i][r]);
            }
}

// ---------------- output projection GEMM (r15 known-good) ----------------
__global__ __launch_bounds__(256) void gemm_out(
    const u16* __restrict__ A, const u16* __restrict__ B,
    const float* __restrict__ bias, float* __restrict__ out)
{
    __shared__ u16 smem[32768];
    const int tid = threadIdx.x;
    const int w = tid >> 6, l = tid & 63;
    const int lr = l & 15, lc = l >> 4;

    const int f = blockIdx.y * 64 + blockIdx.x;
    const int c = f & 7, j = f >> 3;
    const int m0 = (c * 8 + (j & 7)) * 128;
    const int n0 = (j >> 3) * 128;
    const int wm = (w >> 1) * 64, wn = (w & 1) * 64;

    const int srow = w * 8 + (l >> 3);
    const int scol = ((l & 7) ^ (l >> 3)) * 8;
    const u16* gA = A + (size_t)(m0 + srow) * K_DIM + scol;
    const u16* gB = B + (size_t)(n0 + srow) * K_DIM + scol;

    f32x4 acc[4][4] = {};

    auto stage = [&](int k0, int buf) {
        u16* base = smem + buf * 16384;
        #pragma unroll
        for (int g = 0; g < 4; ++g) {
            gload16(gA + (size_t)g * 32 * K_DIM + k0, base + (g * 32 + w * 8) * 64);
            gload16(gB + (size_t)g * 32 * K_DIM + k0, base + 8192 + (g * 32 + w * 8) * 64);
        }
    };

    stage(0, 0);
    int cur = 0;

    for (int k0 = 0; k0 < K_DIM; k0 += 64) {
        __syncthreads();
        if (k0 + 64 < K_DIM) stage(k0 + 64, cur ^ 1);
        const u16* As = smem + cur * 16384;
        const u16* Bs = As + 8192;
        #pragma unroll
        for (int kk = 0; kk < 2; ++kk) {
            s16x8 a[4], b[4];
            #pragma unroll
            for (int i = 0; i < 4; ++i) {
                const int row = wm + i * 16 + lr;
                a[i] = *(const s16x8*)&As[row * 64 + ((kk * 32 + lc * 8) ^ ((row & 7) * 8))];
            }
            #pragma unroll
            for (int jn = 0; jn < 4; ++jn) {
                const int row = wn + jn * 16 + lr;
                b[jn] = *(const s16x8*)&Bs[row * 64 + ((kk * 32 + lc * 8) ^ ((row & 7) * 8))];
            }
            #pragma unroll
            for (int i = 0; i < 4; ++i)
                #pragma unroll
                for (int jn = 0; jn < 4; ++jn)
                    acc[i][jn] = mfma16(a[i], b[jn], acc[i][jn]);
        }
        cur ^= 1;
    }

    #pragma unroll
    for (int jn = 0; jn < 4; ++jn) {
        const int n = n0 + wn + jn * 16 + lr;
        const float bv = bias[n];
        #pragma unroll
        for (int i = 0; i < 4; ++i) {
            #pragma unroll
            for (int r = 0; r < 4; ++r) {
                const int m = m0 + wm + i * 16 + lc * 4 + r;
                out[(size_t)m * 1024 + n] = acc[i][jn][r] + bv;
            }
        }
    }
}

// ---------------- launcher ----------------
extern "C" void kernel_launch(void* const* d_in, const int* in_sizes, int n_in,
                              void* d_out, int out_size, void* d_ws, size_t ws_size,
                              hipStream_t stream) {
    const float* x     = (const float*)d_in[0];
    const float* w_qkv = (const float*)d_in[1];
    const float* b_qkv = (const float*)d_in[2];
    const float* w_out = (const float*)d_in[3];
    const float* b_out = (const float*)d_in[4];
    float* out = (float*)d_out;

    char* ws = (char*)d_ws;
    u16* xb   = (u16*)(ws);                    // 8192x1024 bf16  (16 MB)
    u16* wqb  = (u16*)(ws + 16777216);         // 3072x1024 bf16  (6 MB)
    u16* wob  = (u16*)(ws + 23068672);         // 1024x1024 bf16  (2 MB)
    u16* qws  = (u16*)(ws + 25165824);         // [64][2048][64]  (16 MB)
    u16* kws  = (u16*)(ws + 41943040);         // [64][2048][64]  (16 MB)
    u16* vtws = (u16*)(ws + 58720256);         // [64][64][2048]  (16 MB)
    u16* attn = (u16*)(ws + 75497472);         // 8192x1024 bf16  (16 MB)

    cvt_all<<<dim3(2048), 256, 0, stream>>>(x, w_qkv, w_out, xb, wqb, wob);

    gemm_qkv<<<dim3(64, 24), 256, 0, stream>>>(xb, wqb, b_qkv, qws, kws, vtws);
    attn_fwd<<<dim3(64, 16), 256, 0, stream>>>(qws, kws, vtws, attn);
    gemm_out<<<dim3(64, 8), 256, 0, stream>>>(attn, wob, b_out, out);
}